// Round 10
// baseline (724.369 us; speedup 1.0000x reference)
//
#include <hip/hip_runtime.h>
#include <stdint.h>

// CrossAttention, fp32/bf16 I/O autodetect, all-bf16 MFMA pipeline.
// R15: base = R10 (best, 603us; gemm4/R14 spilled at 256 VGPR and is
// reverted). GEMM-internal surgery stopped (R6-R14: all variants pinned at
// ~904 TF / 36% MfmaUtil). New lever: eliminate the softmax pass.
//  - scores (STAT=1): S stored in log2 domain (alpha'=0.03125*log2e);
//    epilogue computes per-row-block partial (max, sum 2^(v-max)) from
//    ROUNDED values (consistency with stored bf16 S) -> pstats[z][row][xb].
//  - stats_reduce: per row M = max, invS = 1/sum -> mstats[z][row].
//  - PV (NORM=1): A-fragments transformed in-register 2^(s - M_row) (exp
//    on trans pipe, hidden in the ~50% stall slack), output scaled by invS.
//  - softmax_rows dispatch removed (saves its 128MB HBM pass).
// Fused path gated on ws_size >= needB+2MB (pstats lives past SBUF);
// otherwise identical R10 behavior. L2 (N=512) moved to gemm8 (-3us).

typedef __attribute__((ext_vector_type(8))) short bf16x8;
typedef __attribute__((ext_vector_type(4))) float f32x4;
typedef __attribute__((ext_vector_type(8))) unsigned short u16x8;

#define LOG2E_F 1.44269504088896f
#define LN2_F   0.69314718055995f

__device__ __forceinline__ float bf2f(unsigned short u) {
    return __uint_as_float(((unsigned int)u) << 16);
}
__device__ __forceinline__ unsigned short f2bf(float f) {
    unsigned int u = __float_as_uint(f);
    unsigned int r = (u + 0x7fffu + ((u >> 16) & 1u)) >> 16;
    return (unsigned short)r;
}

__device__ __forceinline__ void async16(const void* g, void* l) {
    __builtin_amdgcn_global_load_lds(
        (const __attribute__((address_space(1))) unsigned int*)g,
        (__attribute__((address_space(3))) unsigned int*)l,
        16, 0, 0);
}

// ---------------------------------------------------------------------------
__global__ __launch_bounds__(64) void detect_dtype(
    const unsigned short* __restrict__ w, int* __restrict__ flag)
{
    const int t = threadIdx.x;
    int cnt = 0;
    for (int i = t; i < 4096; i += 64) {
        const unsigned e = (w[i] >> 7) & 0xFF;
        cnt += (e >= 140) ? 1 : 0;
    }
#pragma unroll
    for (int off = 32; off; off >>= 1) cnt += __shfl_xor(cnt, off, 64);
    if (t == 0) flag[0] = (cnt >= 8) ? 1 : 0;
}

// ---------------------------------------------------------------------------
__global__ __launch_bounds__(256) void conv_bias_all(
    const void* b1, const void* b2, const void* b3, const void* b4,
    const void* bq, const void* bk, const void* bv,
    float* __restrict__ out, const int* __restrict__ flag)
{
    const int i = blockIdx.x * 256 + threadIdx.x;
    const int slot = i >> 10, idx = i & 1023;
    if (slot == 1 && idx >= 512) return;
    const void* src = (slot == 0) ? b1 : (slot == 1) ? b2 : (slot == 2) ? b3 :
                      (slot == 3) ? b4 : (slot == 4) ? bq : (slot == 5) ? bk : bv;
    out[i] = (*flag) ? ((const float*)src)[idx]
                     : bf2f(((const unsigned short*)src)[idx]);
}

// ---------------------------------------------------------------------------
__device__ __forceinline__ void wt_body(
    const void* in, unsigned short* out, int R, int C, int f)
{
    __shared__ unsigned short tile[32][33];
    const int bc = blockIdx.x * 32;
    const int br = blockIdx.y * 32;
    const int x = threadIdx.x & 31;
    const int y = threadIdx.x >> 5;
#pragma unroll
    for (int i = 0; i < 4; i++) {
        const int r = y + i * 8;
        unsigned short v;
        if (f) v = f2bf(((const float*)in)[(size_t)(br + r) * C + bc + x]);
        else   v = ((const unsigned short*)in)[(size_t)(br + r) * C + bc + x];
        tile[r][x] = v;
    }
    __syncthreads();
#pragma unroll
    for (int i = 0; i < 4; i++) {
        const int r = y + i * 8;
        out[(size_t)(bc + r) * R + br + x] = tile[x][r];
    }
}

__global__ __launch_bounds__(256) void conv_weight_t7(
    const void* i0, unsigned short* o0, const void* i1, unsigned short* o1,
    const void* i2, unsigned short* o2, const void* i3, unsigned short* o3,
    const void* i4, unsigned short* o4, const void* i5, unsigned short* o5,
    const void* i6, unsigned short* o6, const int* flag)
{
    const int z = blockIdx.z;
    if (z == 5) {
        if (blockIdx.x >= 16) return;
        wt_body(i5, o5, 1024, 512, *flag);
        return;
    }
    if (z == 6) {
        if (blockIdx.y >= 16) return;
        wt_body(i6, o6, 512, 1024, *flag);
        return;
    }
    const void* in = (z == 0) ? i0 : (z == 1) ? i1 : (z == 2) ? i2 : (z == 3) ? i3 : i4;
    unsigned short* out = (z == 0) ? o0 : (z == 1) ? o1 : (z == 2) ? o2 : (z == 3) ? o3 : o4;
    wt_body(in, out, 1024, 1024, *flag);
}

__global__ __launch_bounds__(256) void conv_to_bf16(
    const void* __restrict__ in, unsigned short* __restrict__ out,
    int n, const int* __restrict__ flag)
{
    const int i = (blockIdx.x * 256 + threadIdx.x) * 8;
    if (i >= n) return;
    if (*flag) {
        const float4* p = (const float4*)((const float*)in + i);
        const float4 a = p[0], b = p[1];
        u16x8 o;
        o[0] = f2bf(a.x); o[1] = f2bf(a.y); o[2] = f2bf(a.z); o[3] = f2bf(a.w);
        o[4] = f2bf(b.x); o[5] = f2bf(b.y); o[6] = f2bf(b.z); o[7] = f2bf(b.w);
        *(u16x8*)(out + i) = o;
    } else {
        *(u16x8*)(out + i) = *(const u16x8*)((const unsigned short*)in + i);
    }
}

__global__ __launch_bounds__(256) void write_out(
    const unsigned short* __restrict__ src, void* __restrict__ dst,
    int n, const int* __restrict__ flag)
{
    const int i = (blockIdx.x * 256 + threadIdx.x) * 8;
    if (i >= n) return;
    const u16x8 v = *(const u16x8*)(src + i);
    if (*flag) {
        float4 a, b;
        a.x = bf2f(v[0]); a.y = bf2f(v[1]); a.z = bf2f(v[2]); a.w = bf2f(v[3]);
        b.x = bf2f(v[4]); b.y = bf2f(v[5]); b.z = bf2f(v[6]); b.w = bf2f(v[7]);
        float4* p = (float4*)((float*)dst + i);
        p[0] = a; p[1] = b;
    } else {
        *(u16x8*)((unsigned short*)dst + i) = v;
    }
}

// ---------------------------------------------------------------------------
// Proven 128x128 GEMM: kept for the fallback path.
// ---------------------------------------------------------------------------
template <int RELU, int BIAS, int OUTF, int SWZ>
__global__ __launch_bounds__(256, 2) void gemm_bt(
    const unsigned short* __restrict__ A, const unsigned short* __restrict__ B,
    const float* __restrict__ bias, void* __restrict__ C,
    int M, int N, int K, float alpha,
    long long sA, long long sB, long long sC, const int* __restrict__ flag)
{
    int bxi = blockIdx.x, byi = blockIdx.y;
    if (SWZ) {
        const int id = byi * gridDim.x + bxi;
        bxi = (id >> 3) % gridDim.x;
        byi = (id >> 3) / gridDim.x * 8 + (id & 7);
    }
    const int z = blockIdx.z;
    A += (size_t)z * (size_t)sA;
    B += (size_t)z * (size_t)sB;
    const size_t cofs = (size_t)z * (size_t)sC;

    const int bm = byi * 128;
    const int bn = bxi * 128;
    const int t = threadIdx.x;
    const int lane = t & 63;
    const int w = t >> 6;
    const int wr = (w >> 1) * 64;
    const int wc = (w & 1) * 64;

    __shared__ unsigned short sAt[128 * 32];
    __shared__ unsigned short sBt[128 * 32];

    f32x4 acc[4][4];
#pragma unroll
    for (int i = 0; i < 4; i++)
#pragma unroll
        for (int j = 0; j < 4; j++)
            acc[i][j] = (f32x4){0.f, 0.f, 0.f, 0.f};

    const int tr = t >> 2;
    const int tc = (t & 3) << 3;
    const unsigned short* ga = A + (size_t)(bm + tr) * K + tc;
    const unsigned short* gb = B + (size_t)(bn + tr) * K + tc;
    unsigned short* la = &sAt[tr * 32 + tc];
    unsigned short* lb = &sBt[tr * 32 + tc];

    const int am = wr + (lane & 15);
    const int bn_ = wc + (lane & 15);
    const int ak = (lane >> 4) * 8;

    for (int k0 = 0; k0 < K; k0 += 32) {
        async16(ga, la);
        async16(ga + (size_t)64 * K, la + 64 * 32);
        async16(gb, lb);
        async16(gb + (size_t)64 * K, lb + 64 * 32);
        ga += 32;
        gb += 32;
        __syncthreads();

        bf16x8 af[4], bfr[4];
#pragma unroll
        for (int i = 0; i < 4; i++)
            af[i] = *(const bf16x8*)&sAt[(am + i * 16) * 32 + ak];
#pragma unroll
        for (int j = 0; j < 4; j++)
            bfr[j] = *(const bf16x8*)&sBt[(bn_ + j * 16) * 32 + ak];
#pragma unroll
        for (int i = 0; i < 4; i++)
#pragma unroll
            for (int j = 0; j < 4; j++)
                acc[i][j] = __builtin_amdgcn_mfma_f32_16x16x32_bf16(
                    af[i], bfr[j], acc[i][j], 0, 0, 0);
        __syncthreads();
    }

    const int fl = OUTF ? *flag : 0;
#pragma unroll
    for (int i = 0; i < 4; i++) {
        const int row0 = bm + wr + i * 16 + (lane >> 4) * 4;
#pragma unroll
        for (int j = 0; j < 4; j++) {
            const int col = bn + wc + j * 16 + (lane & 15);
            float bc = 0.f;
            if (BIAS == 1) bc = bias[col];
#pragma unroll
            for (int r = 0; r < 4; r++) {
                float bv = bc;
                if (BIAS == 2) bv = bias[row0 + r];
                float vv = acc[i][j][r] * alpha + bv;
                if (RELU) vv = fmaxf(vv, 0.f);
                const size_t idx = cofs + (size_t)(row0 + r) * N + col;
                if (OUTF && fl) ((float*)C)[idx] = vv;
                else ((unsigned short*)C)[idx] = f2bf(vv);
            }
        }
    }
}

// ---------------------------------------------------------------------------
// R10 gemm8 (proven, 904 TF): 256x256 tile, BK=32, 4 slots, 1 barrier/K-tile.
// R15 adds STAT (scores: partial softmax stats epilogue) and NORM (PV:
// in-register exp2 normalization of the A operand + invS output scaling).
// ---------------------------------------------------------------------------
#define G10_STG(SOFS, KOFS) do {                                               \
    async16(gAs + (KOFS), dA + (SOFS));                                        \
    async16(gAs + (KOFS) + rk128, dA + (SOFS) + 4096);                         \
    async16(gBs + (KOFS), dB + (SOFS));                                        \
    async16(gBs + (KOFS) + rk128, dB + (SOFS) + 4096);                         \
} while (0)

template <int RELU, int BIAS, int OUTF, int SWZ, int STAT, int NORM>
__global__ __launch_bounds__(512, 2) void gemm8(
    const unsigned short* __restrict__ A, const unsigned short* __restrict__ B,
    const float* __restrict__ bias, void* __restrict__ C,
    int M, int N, int K, float alpha,
    long long sA, long long sB, long long sC, const int* __restrict__ flag,
    const float* __restrict__ ms, float* __restrict__ ps)
{
    extern __shared__ unsigned short lds[];
    int bxi = blockIdx.x, byi = blockIdx.y;
    if (SWZ) {
        const int id = byi * gridDim.x + bxi;
        bxi = (id >> 3) % gridDim.x;
        byi = (id >> 3) / gridDim.x * 8 + (id & 7);
    }
    const int z = blockIdx.z;
    A += (size_t)z * (size_t)sA;
    B += (size_t)z * (size_t)sB;
    const size_t cofs = (size_t)z * (size_t)sC;

    const int bm = byi * 256;
    const int bn = bxi * 256;
    const int t = threadIdx.x;
    const int lane = t & 63;
    const int w = t >> 6;
    const int wm = w >> 2;
    const int wn = w & 3;

    const int soct = ((t & 3) ^ ((t >> 3) & 3)) << 3;
    const unsigned short* gAs = A + (size_t)(bm + (t >> 2)) * K + soct;
    const unsigned short* gBs = B + (size_t)(bn + (t >> 2)) * K + soct;
    const size_t rk128 = (size_t)128 * K;
    unsigned short* dA = lds + t * 8;
    unsigned short* dB = lds + 32768 + t * 8;

    const int l15 = lane & 15;
    const int oct = (((lane >> 4) ^ ((lane >> 1) & 3)) << 3);
    const int aoff = (wm * 128 + l15) * 32 + oct;
    const int boff = (wn * 64 + l15) * 32 + oct;

    // NORM: per-fragment-row running max (log2 domain), loaded once.
    float Mm[8];
    if (NORM) {
#pragma unroll
        for (int m = 0; m < 8; m++) {
            const int row = bm + wm * 128 + m * 16 + l15;
            Mm[m] = ms[((size_t)z * M + row) * 2];
        }
    }

    f32x4 acc[8][4];
#pragma unroll
    for (int i = 0; i < 8; i++)
#pragma unroll
        for (int j = 0; j < 4; j++)
            acc[i][j] = (f32x4){0.f, 0.f, 0.f, 0.f};

    G10_STG(0, 0);
    G10_STG(8192, 32);
    asm volatile("s_waitcnt vmcnt(4)" ::: "memory");
    __builtin_amdgcn_s_barrier();
    asm volatile("" ::: "memory");

    const int NT = K >> 5;
    for (int T = 0; T < NT; ++T) {
        if (T + 2 < NT) {
            const int so = ((T + 2) & 3) * 8192;
            const int ko = (T + 2) << 5;
            G10_STG(so, ko);
        }
        const int sr = (T & 3) * 8192;
        const unsigned short* pa = lds + sr + aoff;
        const unsigned short* pb = lds + 32768 + sr + boff;
        bf16x8 bb[4], a[8];
#pragma unroll
        for (int n = 0; n < 4; n++)
            bb[n] = *(const bf16x8*)(pb + n * 512);
#pragma unroll
        for (int m = 0; m < 8; m++)
            a[m] = *(const bf16x8*)(pa + m * 512);
        if (NORM) {
            // P = 2^(s - M_row), elementwise on the A fragments (one row each)
#pragma unroll
            for (int m = 0; m < 8; m++) {
                bf16x8 v = a[m];
                u16x8 o;
#pragma unroll
                for (int e = 0; e < 8; e++) {
                    const float x = bf2f((unsigned short)v[e]);
                    const float p = __expf((x - Mm[m]) * LN2_F);
                    o[e] = f2bf(p);
                }
                a[m] = *(bf16x8*)&o;
            }
        }
        __builtin_amdgcn_s_setprio(1);
#pragma unroll
        for (int m = 0; m < 8; m++)
#pragma unroll
            for (int n = 0; n < 4; n++)
                acc[m][n] = __builtin_amdgcn_mfma_f32_16x16x32_bf16(
                    a[m], bb[n], acc[m][n], 0, 0, 0);
        __builtin_amdgcn_s_setprio(0);
        if (T + 1 < NT) {
            if (T + 2 < NT) {
                asm volatile("s_waitcnt vmcnt(4)" ::: "memory");
            } else {
                asm volatile("s_waitcnt vmcnt(0)" ::: "memory");
            }
            __builtin_amdgcn_s_barrier();
            asm volatile("" ::: "memory");
        }
    }

    const int fl = OUTF ? *flag : 0;
#pragma unroll
    for (int mi = 0; mi < 8; mi++) {
        const int row0 = bm + wm * 128 + mi * 16 + (lane >> 4) * 4;
        float isv[4];
        if (NORM) {
#pragma unroll
            for (int r = 0; r < 4; r++)
                isv[r] = ms[((size_t)z * M + row0 + r) * 2 + 1];
        }
#pragma unroll
        for (int n = 0; n < 4; n++) {
            const int col = bn + wn * 64 + n * 16 + l15;
            float bc = 0.f;
            if (BIAS == 1) bc = bias[col];
#pragma unroll
            for (int r = 0; r < 4; r++) {
                float bv = bc;
                if (BIAS == 2) bv = bias[row0 + r];
                float vv = acc[mi][n][r] * alpha + bv;
                if (NORM) vv *= isv[r];
                if (RELU) vv = fmaxf(vv, 0.f);
                const size_t idx = cofs + (size_t)(row0 + r) * N + col;
                if (OUTF && fl) ((float*)C)[idx] = vv;
                else ((unsigned short*)C)[idx] = f2bf(vv);
            }
        }
    }

    if (STAT) {
        // Partial softmax stats over this block's 256-col slice.
        // Values are in log2 domain; stats computed from ROUNDED values
        // (consistent with the bf16 S just stored).
        __syncthreads();
        float2* sl = (float2*)lds;                 // [256 rows][4 wn]
#pragma unroll
        for (int mi = 0; mi < 8; mi++) {
#pragma unroll
            for (int r = 0; r < 4; r++) {
                float vr[4];
#pragma unroll
                for (int n = 0; n < 4; n++)
                    vr[n] = bf2f(f2bf(acc[mi][n][r] * alpha));
                float mx = fmaxf(fmaxf(vr[0], vr[1]), fmaxf(vr[2], vr[3]));
#pragma unroll
                for (int msk = 1; msk <= 8; msk <<= 1)
                    mx = fmaxf(mx, __shfl_xor(mx, msk, 64));
                float sm = 0.f;
#pragma unroll
                for (int n = 0; n < 4; n++)
                    sm += __expf((vr[n] - mx) * LN2_F);
#pragma unroll
                for (int msk = 1; msk <= 8; msk <<= 1)
                    sm += __shfl_xor(sm, msk, 64);
                if (l15 == 0) {
                    const int rl = wm * 128 + mi * 16 + (lane >> 4) * 4 + r;
                    sl[rl * 4 + wn] = (float2){mx, sm};
                }
            }
        }
        __syncthreads();
        if (t < 256) {
            const float2 p0 = sl[t * 4 + 0], p1 = sl[t * 4 + 1];
            const float2 p2 = sl[t * 4 + 2], p3 = sl[t * 4 + 3];
            float Mx = fmaxf(fmaxf(p0.x, p1.x), fmaxf(p2.x, p3.x));
            float S = p0.y * __expf((p0.x - Mx) * LN2_F)
                    + p1.y * __expf((p1.x - Mx) * LN2_F)
                    + p2.y * __expf((p2.x - Mx) * LN2_F)
                    + p3.y * __expf((p3.x - Mx) * LN2_F);
            float2* o = (float2*)ps;
            o[((size_t)z * M + bm + t) * 8 + bxi] = (float2){Mx, S};
        }
    }
}

// ---------------------------------------------------------------------------
// Combine 8 per-block partials into per-row (M, 1/S). 16384 rows.
// ---------------------------------------------------------------------------
__global__ __launch_bounds__(256) void stats_reduce(
    const float* __restrict__ ps, float* __restrict__ ms)
{
    const int i = blockIdx.x * 256 + threadIdx.x;
    const float2* p = (const float2*)ps + (size_t)i * 8;
    float M = p[0].x;
#pragma unroll
    for (int j = 1; j < 8; j++) M = fmaxf(M, p[j].x);
    float S = 0.f;
#pragma unroll
    for (int j = 0; j < 8; j++)
        S += p[j].y * __expf((p[j].x - M) * LN2_F);
    float2* o = (float2*)ms;
    o[i] = (float2){M, 1.0f / S};
}

// ---------------------------------------------------------------------------
__global__ __launch_bounds__(256) void softmax_rows(unsigned short* S, int n)
{
    const size_t row = blockIdx.x;
    unsigned short* p = S + row * (size_t)n;
    const int t = threadIdx.x;
    const int lane = t & 63;
    const int wave = t >> 6;

    u16x8 v = *(const u16x8*)(p + t * 8);
    float f[8];
    float m = -3.0e38f;
#pragma unroll
    for (int i = 0; i < 8; i++) {
        f[i] = bf2f(v[i]);
        m = fmaxf(m, f[i]);
    }
#pragma unroll
    for (int off = 32; off; off >>= 1) m = fmaxf(m, __shfl_xor(m, off, 64));
    __shared__ float redm[4];
    if (lane == 0) redm[wave] = m;
    __syncthreads();
    m = fmaxf(fmaxf(redm[0], redm[1]), fmaxf(redm[2], redm[3]));

    float e[8];
    float s = 0.f;
#pragma unroll
    for (int i = 0; i < 8; i++) {
        e[i] = __expf(f[i] - m);
        s += e[i];
    }
#pragma unroll
    for (int off = 32; off; off >>= 1) s += __shfl_xor(s, off, 64);
    __shared__ float reds[4];
    if (lane == 0) reds[wave] = s;
    __syncthreads();
    s = reds[0] + reds[1] + reds[2] + reds[3];
    const float inv = 1.0f / s;

    u16x8 o;
#pragma unroll
    for (int i = 0; i < 8; i++) o[i] = f2bf(e[i] * inv);
    *(u16x8*)(p + t * 8) = o;
}

// ---------------------------------------------------------------------------
extern "C" void kernel_launch(void* const* d_in, const int* in_sizes, int n_in,
                              void* d_out, int out_size, void* d_ws, size_t ws_size,
                              hipStream_t stream)
{
    const void* x  = d_in[0];
    const void* y  = d_in[1];
    const void* W1 = d_in[2];
    const void* b1 = d_in[3];
    const void* W2 = d_in[4];
    const void* b2 = d_in[5];
    const void* W3 = d_in[6];
    const void* b3 = d_in[7];
    const void* W4 = d_in[8];
    const void* b4 = d_in[9];
    const void* Wq = d_in[10];
    const void* bq = d_in[11];
    const void* Wk = d_in[12];
    const void* bk = d_in[13];
    const void* Wv = d_in[14];
    const void* bv = d_in[15];

    int* flag = (int*)d_ws;
    float* fb = (float*)((char*)d_ws + 64);
    unsigned short* arena = (unsigned short*)((char*)d_ws + 64 + 7 * 1024 * 4);
    const size_t baseB = 64 + 7 * 1024 * 4;
    const size_t MEG = 1024ull * 1024ull;

    auto needB = [&](int G, bool direct) -> size_t {
        return baseB + 2ull * ((6 + 16 + (size_t)G * 6 + (direct ? 0 : 16)) * MEG);
    };
    int G; bool direct;
    if (ws_size >= needB(8, true))      { G = 8; direct = true;  }
    else if (ws_size >= needB(4, false)) { G = 4; direct = false; }
    else if (ws_size >= needB(2, false)) { G = 2; direct = false; }
    else                                 { G = 1; direct = false; }

    unsigned short* W1t = arena;
    unsigned short* W2t = W1t + 1 * MEG;
    unsigned short* W3t = W2t + MEG / 2;
    unsigned short* W4t = W3t + MEG / 2;
    unsigned short* Wqt = W4t + 1 * MEG;
    unsigned short* Wkt = Wqt + 1 * MEG;
    unsigned short* Wvt = Wkt + 1 * MEG;
    unsigned short* XC  = Wvt + 1 * MEG;
    unsigned short* VT  = XC + 16 * MEG;
    unsigned short* SBUF = VT + (size_t)G * 2 * MEG;
    unsigned short* OUTS = SBUF + (size_t)G * 4 * MEG;

    unsigned short* PA = (unsigned short*)d_out;
    unsigned short* PB = PA + 16 * MEG;

    float* fb1 = fb;
    float* fb2 = fb + 1024;
    float* fb3 = fb + 2048;
    float* fb4 = fb + 3072;
    float* fbq = fb + 4096;
    float* fbk = fb + 5120;
    float* fbv = fb + 6144;

    const dim3 blk(256);
    const dim3 blk8(512);
    const int LDS8 = 131072;
    const int NE = 16 * 1024 * 1024;
    const int Mx = 16384;
    const long long Z0 = 0;
    const long long sQK = 2048ll * 1024;
    const long long sS  = 2048ll * 2048;

    // fused-softmax stats live past SBUF (OUTS region, unused in direct mode)
    const bool fused = direct && (ws_size >= needB(8, true) + 2ull * MEG);
    float* pstats = (float*)OUTS;                    // [8][2048][8] float2 = 1MB
    float* mstats = pstats + 8 * 2048 * 8 * 2;       // [8][2048] float2 = 128KB

    (void)hipFuncSetAttribute((const void*)&gemm8<1, 1, 0, 1, 0, 0>,
                              hipFuncAttributeMaxDynamicSharedMemorySize, LDS8);
    (void)hipFuncSetAttribute((const void*)&gemm8<0, 1, 0, 1, 0, 0>,
                              hipFuncAttributeMaxDynamicSharedMemorySize, LDS8);
    (void)hipFuncSetAttribute((const void*)&gemm8<0, 2, 0, 0, 0, 0>,
                              hipFuncAttributeMaxDynamicSharedMemorySize, LDS8);
    (void)hipFuncSetAttribute((const void*)&gemm8<0, 0, 0, 1, 0, 0>,
                              hipFuncAttributeMaxDynamicSharedMemorySize, LDS8);
    (void)hipFuncSetAttribute((const void*)&gemm8<0, 0, 1, 1, 0, 0>,
                              hipFuncAttributeMaxDynamicSharedMemorySize, LDS8);
    (void)hipFuncSetAttribute((const void*)&gemm8<0, 0, 0, 1, 1, 0>,
                              hipFuncAttributeMaxDynamicSharedMemorySize, LDS8);
    (void)hipFuncSetAttribute((const void*)&gemm8<0, 0, 1, 1, 0, 1>,
                              hipFuncAttributeMaxDynamicSharedMemorySize, LDS8);

    detect_dtype<<<1, 64, 0, stream>>>((const unsigned short*)W1, flag);
    conv_bias_all<<<28, blk, 0, stream>>>(b1, b2, b3, b4, bq, bk, bv, fb, flag);
    conv_weight_t7<<<dim3(32, 32, 7), blk, 0, stream>>>(
        W1, W1t, W4, W4t, Wq, Wqt, Wk, Wkt, Wv, Wvt, W2, W2t, W3, W3t, flag);

    conv_to_bf16<<<8192, blk, 0, stream>>>(x, XC, NE, flag);

    // MLP: L1/L2/L3/L4 on gemm8
    gemm8<1, 1, 0, 1, 0, 0><<<dim3(4, 64), blk8, LDS8, stream>>>(
        XC, W1t, fb1, PA, Mx, 1024, 1024, 1.f, Z0, Z0, Z0, flag, nullptr, nullptr);
    gemm8<1, 1, 0, 1, 0, 0><<<dim3(2, 64), blk8, LDS8, stream>>>(
        PA, W2t, fb2, PB, Mx, 512, 1024, 1.f, Z0, Z0, Z0, flag, nullptr, nullptr);
    gemm8<1, 1, 0, 1, 0, 0><<<dim3(4, 64), blk8, LDS8, stream>>>(
        PB, W3t, fb3, PA, Mx, 1024, 512, 1.f, Z0, Z0, Z0, flag, nullptr, nullptr);
    gemm8<1, 1, 0, 1, 0, 0><<<dim3(4, 64), blk8, LDS8, stream>>>(
        PA, W4t, fb4, PB, Mx, 1024, 1024, 1.f, Z0, Z0, Z0, flag, nullptr, nullptr);

    // q -> PA ; y -> XC ; k -> PB
    gemm8<0, 1, 0, 1, 0, 0><<<dim3(4, 64), blk8, LDS8, stream>>>(
        PB, Wqt, fbq, PA, Mx, 1024, 1024, 1.f, Z0, Z0, Z0, flag, nullptr, nullptr);
    conv_to_bf16<<<8192, blk, 0, stream>>>(y, XC, NE, flag);
    gemm8<0, 1, 0, 1, 0, 0><<<dim3(4, 64), blk8, LDS8, stream>>>(
        XC, Wkt, fbk, PB, Mx, 1024, 1024, 1.f, Z0, Z0, Z0, flag, nullptr, nullptr);

    if (direct) {
        gemm8<0, 2, 0, 0, 0, 0><<<dim3(8, 4, 8), blk8, LDS8, stream>>>(
            Wvt, XC, fbv, VT, 1024, 2048, 1024, 1.f, Z0, sQK, sQK, flag, nullptr, nullptr);
        if (fused) {
            // S in log2 domain; stats epilogue -> pstats; no softmax pass.
            gemm8<0, 0, 0, 1, 1, 0><<<dim3(8, 8, 8), blk8, LDS8, stream>>>(
                PA, PB, nullptr, SBUF, 2048, 2048, 1024, 0.03125f * LOG2E_F,
                sQK, sQK, sS, flag, nullptr, pstats);
            stats_reduce<<<64, blk, 0, stream>>>(pstats, mstats);
            gemm8<0, 0, 1, 1, 0, 1><<<dim3(4, 8, 8), blk8, LDS8, stream>>>(
                SBUF, VT, nullptr, d_out, 2048, 1024, 2048, 1.f,
                sS, sQK, sQK, flag, mstats, nullptr);
        } else {
            gemm8<0, 0, 0, 1, 0, 0><<<dim3(8, 8, 8), blk8, LDS8, stream>>>(
                PA, PB, nullptr, SBUF, 2048, 2048, 1024, 0.03125f,
                sQK, sQK, sS, flag, nullptr, nullptr);
            softmax_rows<<<dim3(8 * 2048), blk, 0, stream>>>(SBUF, 2048);
            gemm8<0, 0, 1, 1, 0, 0><<<dim3(4, 8, 8), blk8, LDS8, stream>>>(
                SBUF, VT, nullptr, d_out, 2048, 1024, 2048, 1.f,
                sS, sQK, sQK, flag, nullptr, nullptr);
        }
    } else {
        for (int g = 0; g < 8; g += G) {
            const size_t off = (size_t)g * 2048 * 1024;
            gemm_bt<0, 2, 0, 0><<<dim3(16, 8, G), blk, 0, stream>>>(
                Wvt, XC + off, fbv, VT, 1024, 2048, 1024, 1.f, Z0, sQK, sQK, flag);
            gemm_bt<0, 0, 0, 1><<<dim3(16, 16, G), blk, 0, stream>>>(
                PA + off, PB + off, nullptr, SBUF, 2048, 2048, 1024, 0.03125f, sQK, sQK, sS, flag);
            softmax_rows<<<dim3(G * 2048), blk, 0, stream>>>(SBUF, 2048);
            gemm_bt<0, 0, 0, 1><<<dim3(8, 16, G), blk, 0, stream>>>(
                SBUF, VT, nullptr, OUTS + off, 2048, 1024, 2048, 1.f, sS, sQK, sQK, flag);
        }
        write_out<<<8192, blk, 0, stream>>>(OUTS, d_out, NE, flag);
    }
}

// Round 11
// 716.804 us; speedup vs baseline: 1.0106x; 1.0106x over previous
//
#include <hip/hip_runtime.h>
#include <stdint.h>

// CrossAttention, fp32/bf16 I/O autodetect, all-bf16 MFMA pipeline.
// R16: softmax fusion, take 2. R15's PV in-loop per-element exp was
// VALU-bound (72% VALUBusy, 187us). Fix: move ALL per-element work out of
// the PV K-loop:
//  - scores (STAT=2): epilogue computes per-row block max Mx (256 cols),
//    stores P = e^(s-Mx) directly (bf16), and pstats[row][xb]=(Mx, sum P).
//  - stats_reduce: per-row global (Mg, 1/S)  [verified correct in R15].
//  - PV (NORM=2): plain MFMA on P; f32 accumulator rescaled by
//    2^(Ml_old-Ml_new) per row only at the 7 xb boundaries (every 8
//    K-tiles) via telescoping O = (sum_i 2^(Ml_i-Ml_7) P_i V_i)
//    * 2^(Ml_7-Mg) * invS (epilogue). ~25cy/K-tile vs R15's 320.
// softmax_rows pass eliminated (~25us). gemm8 loop itself = R10 (proven).
// Fallback + non-fused paths unchanged.

typedef __attribute__((ext_vector_type(8))) short bf16x8;
typedef __attribute__((ext_vector_type(4))) float f32x4;
typedef __attribute__((ext_vector_type(8))) unsigned short u16x8;

#define LOG2E_F 1.44269504088896f
#define LN2_F   0.69314718055995f

__device__ __forceinline__ float bf2f(unsigned short u) {
    return __uint_as_float(((unsigned int)u) << 16);
}
__device__ __forceinline__ unsigned short f2bf(float f) {
    unsigned int u = __float_as_uint(f);
    unsigned int r = (u + 0x7fffu + ((u >> 16) & 1u)) >> 16;
    return (unsigned short)r;
}

__device__ __forceinline__ void async16(const void* g, void* l) {
    __builtin_amdgcn_global_load_lds(
        (const __attribute__((address_space(1))) unsigned int*)g,
        (__attribute__((address_space(3))) unsigned int*)l,
        16, 0, 0);
}

// ---------------------------------------------------------------------------
__global__ __launch_bounds__(64) void detect_dtype(
    const unsigned short* __restrict__ w, int* __restrict__ flag)
{
    const int t = threadIdx.x;
    int cnt = 0;
    for (int i = t; i < 4096; i += 64) {
        const unsigned e = (w[i] >> 7) & 0xFF;
        cnt += (e >= 140) ? 1 : 0;
    }
#pragma unroll
    for (int off = 32; off; off >>= 1) cnt += __shfl_xor(cnt, off, 64);
    if (t == 0) flag[0] = (cnt >= 8) ? 1 : 0;
}

// ---------------------------------------------------------------------------
__global__ __launch_bounds__(256) void conv_bias_all(
    const void* b1, const void* b2, const void* b3, const void* b4,
    const void* bq, const void* bk, const void* bv,
    float* __restrict__ out, const int* __restrict__ flag)
{
    const int i = blockIdx.x * 256 + threadIdx.x;
    const int slot = i >> 10, idx = i & 1023;
    if (slot == 1 && idx >= 512) return;
    const void* src = (slot == 0) ? b1 : (slot == 1) ? b2 : (slot == 2) ? b3 :
                      (slot == 3) ? b4 : (slot == 4) ? bq : (slot == 5) ? bk : bv;
    out[i] = (*flag) ? ((const float*)src)[idx]
                     : bf2f(((const unsigned short*)src)[idx]);
}

// ---------------------------------------------------------------------------
__device__ __forceinline__ void wt_body(
    const void* in, unsigned short* out, int R, int C, int f)
{
    __shared__ unsigned short tile[32][33];
    const int bc = blockIdx.x * 32;
    const int br = blockIdx.y * 32;
    const int x = threadIdx.x & 31;
    const int y = threadIdx.x >> 5;
#pragma unroll
    for (int i = 0; i < 4; i++) {
        const int r = y + i * 8;
        unsigned short v;
        if (f) v = f2bf(((const float*)in)[(size_t)(br + r) * C + bc + x]);
        else   v = ((const unsigned short*)in)[(size_t)(br + r) * C + bc + x];
        tile[r][x] = v;
    }
    __syncthreads();
#pragma unroll
    for (int i = 0; i < 4; i++) {
        const int r = y + i * 8;
        out[(size_t)(bc + r) * R + br + x] = tile[x][r];
    }
}

__global__ __launch_bounds__(256) void conv_weight_t7(
    const void* i0, unsigned short* o0, const void* i1, unsigned short* o1,
    const void* i2, unsigned short* o2, const void* i3, unsigned short* o3,
    const void* i4, unsigned short* o4, const void* i5, unsigned short* o5,
    const void* i6, unsigned short* o6, const int* flag)
{
    const int z = blockIdx.z;
    if (z == 5) {
        if (blockIdx.x >= 16) return;
        wt_body(i5, o5, 1024, 512, *flag);
        return;
    }
    if (z == 6) {
        if (blockIdx.y >= 16) return;
        wt_body(i6, o6, 512, 1024, *flag);
        return;
    }
    const void* in = (z == 0) ? i0 : (z == 1) ? i1 : (z == 2) ? i2 : (z == 3) ? i3 : i4;
    unsigned short* out = (z == 0) ? o0 : (z == 1) ? o1 : (z == 2) ? o2 : (z == 3) ? o3 : o4;
    wt_body(in, out, 1024, 1024, *flag);
}

__global__ __launch_bounds__(256) void conv_to_bf16(
    const void* __restrict__ in, unsigned short* __restrict__ out,
    int n, const int* __restrict__ flag)
{
    const int i = (blockIdx.x * 256 + threadIdx.x) * 8;
    if (i >= n) return;
    if (*flag) {
        const float4* p = (const float4*)((const float*)in + i);
        const float4 a = p[0], b = p[1];
        u16x8 o;
        o[0] = f2bf(a.x); o[1] = f2bf(a.y); o[2] = f2bf(a.z); o[3] = f2bf(a.w);
        o[4] = f2bf(b.x); o[5] = f2bf(b.y); o[6] = f2bf(b.z); o[7] = f2bf(b.w);
        *(u16x8*)(out + i) = o;
    } else {
        *(u16x8*)(out + i) = *(const u16x8*)((const unsigned short*)in + i);
    }
}

__global__ __launch_bounds__(256) void write_out(
    const unsigned short* __restrict__ src, void* __restrict__ dst,
    int n, const int* __restrict__ flag)
{
    const int i = (blockIdx.x * 256 + threadIdx.x) * 8;
    if (i >= n) return;
    const u16x8 v = *(const u16x8*)(src + i);
    if (*flag) {
        float4 a, b;
        a.x = bf2f(v[0]); a.y = bf2f(v[1]); a.z = bf2f(v[2]); a.w = bf2f(v[3]);
        b.x = bf2f(v[4]); b.y = bf2f(v[5]); b.z = bf2f(v[6]); b.w = bf2f(v[7]);
        float4* p = (float4*)((float*)dst + i);
        p[0] = a; p[1] = b;
    } else {
        *(u16x8*)((unsigned short*)dst + i) = v;
    }
}

// ---------------------------------------------------------------------------
// Proven 128x128 GEMM: kept for the fallback path.
// ---------------------------------------------------------------------------
template <int RELU, int BIAS, int OUTF, int SWZ>
__global__ __launch_bounds__(256, 2) void gemm_bt(
    const unsigned short* __restrict__ A, const unsigned short* __restrict__ B,
    const float* __restrict__ bias, void* __restrict__ C,
    int M, int N, int K, float alpha,
    long long sA, long long sB, long long sC, const int* __restrict__ flag)
{
    int bxi = blockIdx.x, byi = blockIdx.y;
    if (SWZ) {
        const int id = byi * gridDim.x + bxi;
        bxi = (id >> 3) % gridDim.x;
        byi = (id >> 3) / gridDim.x * 8 + (id & 7);
    }
    const int z = blockIdx.z;
    A += (size_t)z * (size_t)sA;
    B += (size_t)z * (size_t)sB;
    const size_t cofs = (size_t)z * (size_t)sC;

    const int bm = byi * 128;
    const int bn = bxi * 128;
    const int t = threadIdx.x;
    const int lane = t & 63;
    const int w = t >> 6;
    const int wr = (w >> 1) * 64;
    const int wc = (w & 1) * 64;

    __shared__ unsigned short sAt[128 * 32];
    __shared__ unsigned short sBt[128 * 32];

    f32x4 acc[4][4];
#pragma unroll
    for (int i = 0; i < 4; i++)
#pragma unroll
        for (int j = 0; j < 4; j++)
            acc[i][j] = (f32x4){0.f, 0.f, 0.f, 0.f};

    const int tr = t >> 2;
    const int tc = (t & 3) << 3;
    const unsigned short* ga = A + (size_t)(bm + tr) * K + tc;
    const unsigned short* gb = B + (size_t)(bn + tr) * K + tc;
    unsigned short* la = &sAt[tr * 32 + tc];
    unsigned short* lb = &sBt[tr * 32 + tc];

    const int am = wr + (lane & 15);
    const int bn_ = wc + (lane & 15);
    const int ak = (lane >> 4) * 8;

    for (int k0 = 0; k0 < K; k0 += 32) {
        async16(ga, la);
        async16(ga + (size_t)64 * K, la + 64 * 32);
        async16(gb, lb);
        async16(gb + (size_t)64 * K, lb + 64 * 32);
        ga += 32;
        gb += 32;
        __syncthreads();

        bf16x8 af[4], bfr[4];
#pragma unroll
        for (int i = 0; i < 4; i++)
            af[i] = *(const bf16x8*)&sAt[(am + i * 16) * 32 + ak];
#pragma unroll
        for (int j = 0; j < 4; j++)
            bfr[j] = *(const bf16x8*)&sBt[(bn_ + j * 16) * 32 + ak];
#pragma unroll
        for (int i = 0; i < 4; i++)
#pragma unroll
            for (int j = 0; j < 4; j++)
                acc[i][j] = __builtin_amdgcn_mfma_f32_16x16x32_bf16(
                    af[i], bfr[j], acc[i][j], 0, 0, 0);
        __syncthreads();
    }

    const int fl = OUTF ? *flag : 0;
#pragma unroll
    for (int i = 0; i < 4; i++) {
        const int row0 = bm + wr + i * 16 + (lane >> 4) * 4;
#pragma unroll
        for (int j = 0; j < 4; j++) {
            const int col = bn + wc + j * 16 + (lane & 15);
            float bc = 0.f;
            if (BIAS == 1) bc = bias[col];
#pragma unroll
            for (int r = 0; r < 4; r++) {
                float bv = bc;
                if (BIAS == 2) bv = bias[row0 + r];
                float vv = acc[i][j][r] * alpha + bv;
                if (RELU) vv = fmaxf(vv, 0.f);
                const size_t idx = cofs + (size_t)(row0 + r) * N + col;
                if (OUTF && fl) ((float*)C)[idx] = vv;
                else ((unsigned short*)C)[idx] = f2bf(vv);
            }
        }
    }
}

// ---------------------------------------------------------------------------
// R10 gemm8 (proven, 904 TF): 256x256 tile, BK=32, 4 slots, 1 barrier/K-tile.
// R16: STAT=2 (scores: epilogue row-max + store P=e^(s-Mx) + pstats);
//      NORM=2 (PV: xb-boundary f32 accumulator rescale + epilogue scale).
// ---------------------------------------------------------------------------
#define G10_STG(SOFS, KOFS) do {                                               \
    async16(gAs + (KOFS), dA + (SOFS));                                        \
    async16(gAs + (KOFS) + rk128, dA + (SOFS) + 4096);                         \
    async16(gBs + (KOFS), dB + (SOFS));                                        \
    async16(gBs + (KOFS) + rk128, dB + (SOFS) + 4096);                         \
} while (0)

template <int RELU, int BIAS, int OUTF, int SWZ, int STAT, int NORM>
__global__ __launch_bounds__(512, 2) void gemm8(
    const unsigned short* __restrict__ A, const unsigned short* __restrict__ B,
    const float* __restrict__ bias, void* __restrict__ C,
    int M, int N, int K, float alpha,
    long long sA, long long sB, long long sC, const int* __restrict__ flag,
    const float* __restrict__ ms, float* __restrict__ ps)
{
    extern __shared__ unsigned short lds[];
    int bxi = blockIdx.x, byi = blockIdx.y;
    if (SWZ) {
        const int id = byi * gridDim.x + bxi;
        bxi = (id >> 3) % gridDim.x;
        byi = (id >> 3) / gridDim.x * 8 + (id & 7);
    }
    const int z = blockIdx.z;
    A += (size_t)z * (size_t)sA;
    B += (size_t)z * (size_t)sB;
    const size_t cofs = (size_t)z * (size_t)sC;

    const int bm = byi * 256;
    const int bn = bxi * 256;
    const int t = threadIdx.x;
    const int lane = t & 63;
    const int w = t >> 6;
    const int wm = w >> 2;
    const int wn = w & 3;
    const int l15 = lane & 15;
    const int l4 = lane >> 4;

    const int soct = ((t & 3) ^ ((t >> 3) & 3)) << 3;
    const unsigned short* gAs = A + (size_t)(bm + (t >> 2)) * K + soct;
    const unsigned short* gBs = B + (size_t)(bn + (t >> 2)) * K + soct;
    const size_t rk128 = (size_t)128 * K;
    unsigned short* dA = lds + t * 8;
    unsigned short* dB = lds + 32768 + t * 8;

    const int oct = (((lane >> 4) ^ ((lane >> 1) & 3)) << 3);
    const int aoff = (wm * 128 + l15) * 32 + oct;
    const int boff = (wn * 64 + l15) * 32 + oct;

    // NORM==2: running per-row local max (from pstats xb=0).
    float Ml[8][4];
    if (NORM == 2) {
#pragma unroll
        for (int mi = 0; mi < 8; mi++)
#pragma unroll
            for (int r = 0; r < 4; r++) {
                const int row = bm + wm * 128 + mi * 16 + l4 * 4 + r;
                Ml[mi][r] = ps[(((size_t)z * M + row) * 8 + 0) * 2];
            }
    }

    f32x4 acc[8][4];
#pragma unroll
    for (int i = 0; i < 8; i++)
#pragma unroll
        for (int j = 0; j < 4; j++)
            acc[i][j] = (f32x4){0.f, 0.f, 0.f, 0.f};

    G10_STG(0, 0);
    G10_STG(8192, 32);
    asm volatile("s_waitcnt vmcnt(4)" ::: "memory");
    __builtin_amdgcn_s_barrier();
    asm volatile("" ::: "memory");

    const int NT = K >> 5;
    for (int T = 0; T < NT; ++T) {
        if (NORM == 2 && T > 0 && (T & 7) == 0) {
            // xb boundary: rescale accumulator to the new local-max frame.
            const int xb = T >> 3;
#pragma unroll
            for (int mi = 0; mi < 8; mi++)
#pragma unroll
                for (int r = 0; r < 4; r++) {
                    const int row = bm + wm * 128 + mi * 16 + l4 * 4 + r;
                    const float mn = ps[(((size_t)z * M + row) * 8 + xb) * 2];
                    const float rat = __expf((Ml[mi][r] - mn) * LN2_F);
                    Ml[mi][r] = mn;
#pragma unroll
                    for (int n = 0; n < 4; n++)
                        acc[mi][n][r] *= rat;
                }
        }
        if (T + 2 < NT) {
            const int so = ((T + 2) & 3) * 8192;
            const int ko = (T + 2) << 5;
            G10_STG(so, ko);
        }
        const int sr = (T & 3) * 8192;
        const unsigned short* pa = lds + sr + aoff;
        const unsigned short* pb = lds + 32768 + sr + boff;
        bf16x8 bb[4], a[8];
#pragma unroll
        for (int n = 0; n < 4; n++)
            bb[n] = *(const bf16x8*)(pb + n * 512);
#pragma unroll
        for (int m = 0; m < 8; m++)
            a[m] = *(const bf16x8*)(pa + m * 512);
        __builtin_amdgcn_s_setprio(1);
#pragma unroll
        for (int m = 0; m < 8; m++)
#pragma unroll
            for (int n = 0; n < 4; n++)
                acc[m][n] = __builtin_amdgcn_mfma_f32_16x16x32_bf16(
                    a[m], bb[n], acc[m][n], 0, 0, 0);
        __builtin_amdgcn_s_setprio(0);
        if (T + 1 < NT) {
            if (T + 2 < NT) {
                asm volatile("s_waitcnt vmcnt(4)" ::: "memory");
            } else {
                asm volatile("s_waitcnt vmcnt(0)" ::: "memory");
            }
            __builtin_amdgcn_s_barrier();
            asm volatile("" ::: "memory");
        }
    }

    if (STAT != 2) {
        const int fl = OUTF ? *flag : 0;
#pragma unroll
        for (int mi = 0; mi < 8; mi++) {
            const int row0 = bm + wm * 128 + mi * 16 + l4 * 4;
            float isv[4];
            if (NORM == 2) {
#pragma unroll
                for (int r = 0; r < 4; r++) {
                    const float2 g =
                        ((const float2*)ms)[(size_t)z * M + row0 + r];
                    isv[r] = __expf((Ml[mi][r] - g.x) * LN2_F) * g.y;
                }
            }
#pragma unroll
            for (int n = 0; n < 4; n++) {
                const int col = bn + wn * 64 + n * 16 + l15;
                float bc = 0.f;
                if (BIAS == 1) bc = bias[col];
#pragma unroll
                for (int r = 0; r < 4; r++) {
                    float bv = bc;
                    if (BIAS == 2) bv = bias[row0 + r];
                    float vv = acc[mi][n][r] * alpha + bv;
                    if (NORM == 2) vv *= isv[r];
                    if (RELU) vv = fmaxf(vv, 0.f);
                    const size_t idx = cofs + (size_t)(row0 + r) * N + col;
                    if (OUTF && fl) ((float*)C)[idx] = vv;
                    else ((unsigned short*)C)[idx] = f2bf(vv);
                }
            }
        }
    } else {
        // STAT==2: per-row block max over 256 cols, store P=e^(s-Mx),
        // partial (Mx, sum P) -> pstats. lds is free after the K-loop.
        __syncthreads();
        float2* sl = (float2*)lds;                     // [256][4] = 8KB
        float* sm2 = (float*)((char*)lds + 8192);      // [256] Mx
        // phase A: per-(row, wn) max over 4 n-frags and 16 lanes
#pragma unroll
        for (int mi = 0; mi < 8; mi++) {
#pragma unroll
            for (int r = 0; r < 4; r++) {
                float mx = acc[mi][0][r];
#pragma unroll
                for (int n = 1; n < 4; n++) mx = fmaxf(mx, acc[mi][n][r]);
                mx *= alpha;
#pragma unroll
                for (int msk = 1; msk <= 8; msk <<= 1)
                    mx = fmaxf(mx, __shfl_xor(mx, msk, 64));
                if (l15 == 0) {
                    const int rl = wm * 128 + mi * 16 + l4 * 4 + r;
                    sl[rl * 4 + wn].x = mx;
                }
            }
        }
        __syncthreads();
        if (t < 256) {
            const float Mx = fmaxf(fmaxf(sl[t * 4 + 0].x, sl[t * 4 + 1].x),
                                   fmaxf(sl[t * 4 + 2].x, sl[t * 4 + 3].x));
            sm2[t] = Mx;
        }
        __syncthreads();
        // phase C: store rounded P, accumulate row-partial sums
#pragma unroll
        for (int mi = 0; mi < 8; mi++) {
#pragma unroll
            for (int r = 0; r < 4; r++) {
                const int rl = wm * 128 + mi * 16 + l4 * 4 + r;
                const float Mx = sm2[rl];
                float s = 0.f;
#pragma unroll
                for (int n = 0; n < 4; n++) {
                    const float v = acc[mi][n][r] * alpha;
                    const unsigned short pbv =
                        f2bf(__expf((v - Mx) * LN2_F));
                    s += bf2f(pbv);
                    const int col = bn + wn * 64 + n * 16 + l15;
                    ((unsigned short*)C)[cofs + (size_t)(bm + rl) * N + col]
                        = pbv;
                }
#pragma unroll
                for (int msk = 1; msk <= 8; msk <<= 1)
                    s += __shfl_xor(s, msk, 64);
                if (l15 == 0) sl[rl * 4 + wn].y = s;
            }
        }
        __syncthreads();
        if (t < 256) {
            const float S = sl[t * 4 + 0].y + sl[t * 4 + 1].y
                          + sl[t * 4 + 2].y + sl[t * 4 + 3].y;
            ((float2*)ps)[((size_t)z * M + bm + t) * 8 + bxi] =
                (float2){sm2[t], S};
        }
    }
}

// ---------------------------------------------------------------------------
// Combine 8 per-block partials into per-row (Mg, 1/S). 16384 rows.
// ---------------------------------------------------------------------------
__global__ __launch_bounds__(256) void stats_reduce(
    const float* __restrict__ ps, float* __restrict__ ms)
{
    const int i = blockIdx.x * 256 + threadIdx.x;
    const float2* p = (const float2*)ps + (size_t)i * 8;
    float M = p[0].x;
#pragma unroll
    for (int j = 1; j < 8; j++) M = fmaxf(M, p[j].x);
    float S = 0.f;
#pragma unroll
    for (int j = 0; j < 8; j++)
        S += p[j].y * __expf((p[j].x - M) * LN2_F);
    float2* o = (float2*)ms;
    o[i] = (float2){M, 1.0f / S};
}

// ---------------------------------------------------------------------------
__global__ __launch_bounds__(256) void softmax_rows(unsigned short* S, int n)
{
    const size_t row = blockIdx.x;
    unsigned short* p = S + row * (size_t)n;
    const int t = threadIdx.x;
    const int lane = t & 63;
    const int wave = t >> 6;

    u16x8 v = *(const u16x8*)(p + t * 8);
    float f[8];
    float m = -3.0e38f;
#pragma unroll
    for (int i = 0; i < 8; i++) {
        f[i] = bf2f(v[i]);
        m = fmaxf(m, f[i]);
    }
#pragma unroll
    for (int off = 32; off; off >>= 1) m = fmaxf(m, __shfl_xor(m, off, 64));
    __shared__ float redm[4];
    if (lane == 0) redm[wave] = m;
    __syncthreads();
    m = fmaxf(fmaxf(redm[0], redm[1]), fmaxf(redm[2], redm[3]));

    float e[8];
    float s = 0.f;
#pragma unroll
    for (int i = 0; i < 8; i++) {
        e[i] = __expf(f[i] - m);
        s += e[i];
    }
#pragma unroll
    for (int off = 32; off; off >>= 1) s += __shfl_xor(s, off, 64);
    __shared__ float reds[4];
    if (lane == 0) reds[wave] = s;
    __syncthreads();
    s = reds[0] + reds[1] + reds[2] + reds[3];
    const float inv = 1.0f / s;

    u16x8 o;
#pragma unroll
    for (int i = 0; i < 8; i++) o[i] = f2bf(e[i] * inv);
    *(u16x8*)(p + t * 8) = o;
}

// ---------------------------------------------------------------------------
extern "C" void kernel_launch(void* const* d_in, const int* in_sizes, int n_in,
                              void* d_out, int out_size, void* d_ws, size_t ws_size,
                              hipStream_t stream)
{
    const void* x  = d_in[0];
    const void* y  = d_in[1];
    const void* W1 = d_in[2];
    const void* b1 = d_in[3];
    const void* W2 = d_in[4];
    const void* b2 = d_in[5];
    const void* W3 = d_in[6];
    const void* b3 = d_in[7];
    const void* W4 = d_in[8];
    const void* b4 = d_in[9];
    const void* Wq = d_in[10];
    const void* bq = d_in[11];
    const void* Wk = d_in[12];
    const void* bk = d_in[13];
    const void* Wv = d_in[14];
    const void* bv = d_in[15];

    int* flag = (int*)d_ws;
    float* fb = (float*)((char*)d_ws + 64);
    unsigned short* arena = (unsigned short*)((char*)d_ws + 64 + 7 * 1024 * 4);
    const size_t baseB = 64 + 7 * 1024 * 4;
    const size_t MEG = 1024ull * 1024ull;

    auto needB = [&](int G, bool direct) -> size_t {
        return baseB + 2ull * ((6 + 16 + (size_t)G * 6 + (direct ? 0 : 16)) * MEG);
    };
    int G; bool direct;
    if (ws_size >= needB(8, true))      { G = 8; direct = true;  }
    else if (ws_size >= needB(4, false)) { G = 4; direct = false; }
    else if (ws_size >= needB(2, false)) { G = 2; direct = false; }
    else                                 { G = 1; direct = false; }

    unsigned short* W1t = arena;
    unsigned short* W2t = W1t + 1 * MEG;
    unsigned short* W3t = W2t + MEG / 2;
    unsigned short* W4t = W3t + MEG / 2;
    unsigned short* Wqt = W4t + 1 * MEG;
    unsigned short* Wkt = Wqt + 1 * MEG;
    unsigned short* Wvt = Wkt + 1 * MEG;
    unsigned short* XC  = Wvt + 1 * MEG;
    unsigned short* VT  = XC + 16 * MEG;
    unsigned short* SBUF = VT + (size_t)G * 2 * MEG;
    unsigned short* OUTS = SBUF + (size_t)G * 4 * MEG;

    unsigned short* PA = (unsigned short*)d_out;
    unsigned short* PB = PA + 16 * MEG;

    float* fb1 = fb;
    float* fb2 = fb + 1024;
    float* fb3 = fb + 2048;
    float* fb4 = fb + 3072;
    float* fbq = fb + 4096;
    float* fbk = fb + 5120;
    float* fbv = fb + 6144;

    const dim3 blk(256);
    const dim3 blk8(512);
    const int LDS8 = 131072;
    const int NE = 16 * 1024 * 1024;
    const int Mx = 16384;
    const long long Z0 = 0;
    const long long sQK = 2048ll * 1024;
    const long long sS  = 2048ll * 2048;

    // fused-softmax stats live past SBUF (OUTS region, unused in direct mode)
    const bool fused = direct && (ws_size >= needB(8, true) + 2ull * MEG);
    float* pstats = (float*)OUTS;                    // [8][2048][8] float2 = 1MB
    float* mstats = pstats + 8 * 2048 * 8 * 2;       // [8][2048] float2 = 128KB

    (void)hipFuncSetAttribute((const void*)&gemm8<1, 1, 0, 1, 0, 0>,
                              hipFuncAttributeMaxDynamicSharedMemorySize, LDS8);
    (void)hipFuncSetAttribute((const void*)&gemm8<0, 1, 0, 1, 0, 0>,
                              hipFuncAttributeMaxDynamicSharedMemorySize, LDS8);
    (void)hipFuncSetAttribute((const void*)&gemm8<0, 2, 0, 0, 0, 0>,
                              hipFuncAttributeMaxDynamicSharedMemorySize, LDS8);
    (void)hipFuncSetAttribute((const void*)&gemm8<0, 0, 0, 1, 0, 0>,
                              hipFuncAttributeMaxDynamicSharedMemorySize, LDS8);
    (void)hipFuncSetAttribute((const void*)&gemm8<0, 0, 1, 1, 0, 0>,
                              hipFuncAttributeMaxDynamicSharedMemorySize, LDS8);
    (void)hipFuncSetAttribute((const void*)&gemm8<0, 0, 0, 1, 2, 0>,
                              hipFuncAttributeMaxDynamicSharedMemorySize, LDS8);
    (void)hipFuncSetAttribute((const void*)&gemm8<0, 0, 1, 1, 0, 2>,
                              hipFuncAttributeMaxDynamicSharedMemorySize, LDS8);

    detect_dtype<<<1, 64, 0, stream>>>((const unsigned short*)W1, flag);
    conv_bias_all<<<28, blk, 0, stream>>>(b1, b2, b3, b4, bq, bk, bv, fb, flag);
    conv_weight_t7<<<dim3(32, 32, 7), blk, 0, stream>>>(
        W1, W1t, W4, W4t, Wq, Wqt, Wk, Wkt, Wv, Wvt, W2, W2t, W3, W3t, flag);

    conv_to_bf16<<<8192, blk, 0, stream>>>(x, XC, NE, flag);

    // MLP: all layers on gemm8
    gemm8<1, 1, 0, 1, 0, 0><<<dim3(4, 64), blk8, LDS8, stream>>>(
        XC, W1t, fb1, PA, Mx, 1024, 1024, 1.f, Z0, Z0, Z0, flag, nullptr, nullptr);
    gemm8<1, 1, 0, 1, 0, 0><<<dim3(2, 64), blk8, LDS8, stream>>>(
        PA, W2t, fb2, PB, Mx, 512, 1024, 1.f, Z0, Z0, Z0, flag, nullptr, nullptr);
    gemm8<1, 1, 0, 1, 0, 0><<<dim3(4, 64), blk8, LDS8, stream>>>(
        PB, W3t, fb3, PA, Mx, 1024, 512, 1.f, Z0, Z0, Z0, flag, nullptr, nullptr);
    gemm8<1, 1, 0, 1, 0, 0><<<dim3(4, 64), blk8, LDS8, stream>>>(
        PA, W4t, fb4, PB, Mx, 1024, 1024, 1.f, Z0, Z0, Z0, flag, nullptr, nullptr);

    // q -> PA ; y -> XC ; k -> PB
    gemm8<0, 1, 0, 1, 0, 0><<<dim3(4, 64), blk8, LDS8, stream>>>(
        PB, Wqt, fbq, PA, Mx, 1024, 1024, 1.f, Z0, Z0, Z0, flag, nullptr, nullptr);
    conv_to_bf16<<<8192, blk, 0, stream>>>(y, XC, NE, flag);
    gemm8<0, 1, 0, 1, 0, 0><<<dim3(4, 64), blk8, LDS8, stream>>>(
        XC, Wkt, fbk, PB, Mx, 1024, 1024, 1.f, Z0, Z0, Z0, flag, nullptr, nullptr);

    if (direct) {
        gemm8<0, 2, 0, 0, 0, 0><<<dim3(8, 4, 8), blk8, LDS8, stream>>>(
            Wvt, XC, fbv, VT, 1024, 2048, 1024, 1.f, Z0, sQK, sQK, flag, nullptr, nullptr);
        if (fused) {
            // scores: store P = e^(s - Mx_block) + pstats; no softmax pass.
            gemm8<0, 0, 0, 1, 2, 0><<<dim3(8, 8, 8), blk8, LDS8, stream>>>(
                PA, PB, nullptr, SBUF, 2048, 2048, 1024, 0.03125f * LOG2E_F,
                sQK, sQK, sS, flag, nullptr, pstats);
            stats_reduce<<<64, blk, 0, stream>>>(pstats, mstats);
            gemm8<0, 0, 1, 1, 0, 2><<<dim3(4, 8, 8), blk8, LDS8, stream>>>(
                SBUF, VT, nullptr, d_out, 2048, 1024, 2048, 1.f,
                sS, sQK, sQK, flag, mstats, pstats);
        } else {
            gemm8<0, 0, 0, 1, 0, 0><<<dim3(8, 8, 8), blk8, LDS8, stream>>>(
                PA, PB, nullptr, SBUF, 2048, 2048, 1024, 0.03125f,
                sQK, sQK, sS, flag, nullptr, nullptr);
            softmax_rows<<<dim3(8 * 2048), blk, 0, stream>>>(SBUF, 2048);
            gemm8<0, 0, 1, 1, 0, 0><<<dim3(4, 8, 8), blk8, LDS8, stream>>>(
                SBUF, VT, nullptr, d_out, 2048, 1024, 2048, 1.f,
                sS, sQK, sQK, flag, nullptr, nullptr);
        }
    } else {
        for (int g = 0; g < 8; g += G) {
            const size_t off = (size_t)g * 2048 * 1024;
            gemm_bt<0, 2, 0, 0><<<dim3(16, 8, G), blk, 0, stream>>>(
                Wvt, XC + off, fbv, VT, 1024, 2048, 1024, 1.f, Z0, sQK, sQK, flag);
            gemm_bt<0, 0, 0, 1><<<dim3(16, 16, G), blk, 0, stream>>>(
                PA + off, PB + off, nullptr, SBUF, 2048, 2048, 1024, 0.03125f, sQK, sQK, sS, flag);
            softmax_rows<<<dim3(G * 2048), blk, 0, stream>>>(SBUF, 2048);
            gemm_bt<0, 0, 0, 1><<<dim3(8, 16, G), blk, 0, stream>>>(
                SBUF, VT, nullptr, OUTS + off, 2048, 1024, 2048, 1.f, sS, sQK, sQK, flag);
        }
        write_out<<<8192, blk, 0, stream>>>(OUTS, d_out, NE, flag);
    }
}

// Round 12
// 609.056 us; speedup vs baseline: 1.1893x; 1.1769x over previous
//
#include <hip/hip_runtime.h>
#include <stdint.h>

// CrossAttention, fp32/bf16 I/O autodetect, all-bf16 MFMA pipeline.
// R17 = exact revert to R10 (session-best, 603us) as the terminal state.
// Ledger: R7-R13 schedule/wait/occupancy variants all pinned at ~904 TF
// (36% MfmaUtil) on the big GEMMs; R12 proved locality is not the limit
// (fetch -66%, time +19%); R14 (4-wave) spills at the 256-VGPR cap;
// R15/R16 softmax-fusion variants cost +80..+137us vs the 25us pass they
// remove. The 256x256 / BK=32 / 4-slot / 1-barrier-per-K-tile gemm8 below
// is the verified optimum of this structure family.

typedef __attribute__((ext_vector_type(8))) short bf16x8;
typedef __attribute__((ext_vector_type(4))) float f32x4;
typedef __attribute__((ext_vector_type(8))) unsigned short u16x8;

__device__ __forceinline__ float bf2f(unsigned short u) {
    return __uint_as_float(((unsigned int)u) << 16);
}
__device__ __forceinline__ unsigned short f2bf(float f) {
    unsigned int u = __float_as_uint(f);
    unsigned int r = (u + 0x7fffu + ((u >> 16) & 1u)) >> 16;
    return (unsigned short)r;
}

__device__ __forceinline__ void async16(const void* g, void* l) {
    __builtin_amdgcn_global_load_lds(
        (const __attribute__((address_space(1))) unsigned int*)g,
        (__attribute__((address_space(3))) unsigned int*)l,
        16, 0, 0);
}

// ---------------------------------------------------------------------------
__global__ __launch_bounds__(64) void detect_dtype(
    const unsigned short* __restrict__ w, int* __restrict__ flag)
{
    const int t = threadIdx.x;
    int cnt = 0;
    for (int i = t; i < 4096; i += 64) {
        const unsigned e = (w[i] >> 7) & 0xFF;
        cnt += (e >= 140) ? 1 : 0;
    }
#pragma unroll
    for (int off = 32; off; off >>= 1) cnt += __shfl_xor(cnt, off, 64);
    if (t == 0) flag[0] = (cnt >= 8) ? 1 : 0;
}

// ---------------------------------------------------------------------------
__global__ __launch_bounds__(256) void conv_bias_all(
    const void* b1, const void* b2, const void* b3, const void* b4,
    const void* bq, const void* bk, const void* bv,
    float* __restrict__ out, const int* __restrict__ flag)
{
    const int i = blockIdx.x * 256 + threadIdx.x;
    const int slot = i >> 10, idx = i & 1023;
    if (slot == 1 && idx >= 512) return;
    const void* src = (slot == 0) ? b1 : (slot == 1) ? b2 : (slot == 2) ? b3 :
                      (slot == 3) ? b4 : (slot == 4) ? bq : (slot == 5) ? bk : bv;
    out[i] = (*flag) ? ((const float*)src)[idx]
                     : bf2f(((const unsigned short*)src)[idx]);
}

// ---------------------------------------------------------------------------
__device__ __forceinline__ void wt_body(
    const void* in, unsigned short* out, int R, int C, int f)
{
    __shared__ unsigned short tile[32][33];
    const int bc = blockIdx.x * 32;
    const int br = blockIdx.y * 32;
    const int x = threadIdx.x & 31;
    const int y = threadIdx.x >> 5;
#pragma unroll
    for (int i = 0; i < 4; i++) {
        const int r = y + i * 8;
        unsigned short v;
        if (f) v = f2bf(((const float*)in)[(size_t)(br + r) * C + bc + x]);
        else   v = ((const unsigned short*)in)[(size_t)(br + r) * C + bc + x];
        tile[r][x] = v;
    }
    __syncthreads();
#pragma unroll
    for (int i = 0; i < 4; i++) {
        const int r = y + i * 8;
        out[(size_t)(bc + r) * R + br + x] = tile[x][r];
    }
}

__global__ __launch_bounds__(256) void conv_weight_t7(
    const void* i0, unsigned short* o0, const void* i1, unsigned short* o1,
    const void* i2, unsigned short* o2, const void* i3, unsigned short* o3,
    const void* i4, unsigned short* o4, const void* i5, unsigned short* o5,
    const void* i6, unsigned short* o6, const int* flag)
{
    const int z = blockIdx.z;
    if (z == 5) {
        if (blockIdx.x >= 16) return;
        wt_body(i5, o5, 1024, 512, *flag);
        return;
    }
    if (z == 6) {
        if (blockIdx.y >= 16) return;
        wt_body(i6, o6, 512, 1024, *flag);
        return;
    }
    const void* in = (z == 0) ? i0 : (z == 1) ? i1 : (z == 2) ? i2 : (z == 3) ? i3 : i4;
    unsigned short* out = (z == 0) ? o0 : (z == 1) ? o1 : (z == 2) ? o2 : (z == 3) ? o3 : o4;
    wt_body(in, out, 1024, 1024, *flag);
}

__global__ __launch_bounds__(256) void conv_to_bf16(
    const void* __restrict__ in, unsigned short* __restrict__ out,
    int n, const int* __restrict__ flag)
{
    const int i = (blockIdx.x * 256 + threadIdx.x) * 8;
    if (i >= n) return;
    if (*flag) {
        const float4* p = (const float4*)((const float*)in + i);
        const float4 a = p[0], b = p[1];
        u16x8 o;
        o[0] = f2bf(a.x); o[1] = f2bf(a.y); o[2] = f2bf(a.z); o[3] = f2bf(a.w);
        o[4] = f2bf(b.x); o[5] = f2bf(b.y); o[6] = f2bf(b.z); o[7] = f2bf(b.w);
        *(u16x8*)(out + i) = o;
    } else {
        *(u16x8*)(out + i) = *(const u16x8*)((const unsigned short*)in + i);
    }
}

__global__ __launch_bounds__(256) void write_out(
    const unsigned short* __restrict__ src, void* __restrict__ dst,
    int n, const int* __restrict__ flag)
{
    const int i = (blockIdx.x * 256 + threadIdx.x) * 8;
    if (i >= n) return;
    const u16x8 v = *(const u16x8*)(src + i);
    if (*flag) {
        float4 a, b;
        a.x = bf2f(v[0]); a.y = bf2f(v[1]); a.z = bf2f(v[2]); a.w = bf2f(v[3]);
        b.x = bf2f(v[4]); b.y = bf2f(v[5]); b.z = bf2f(v[6]); b.w = bf2f(v[7]);
        float4* p = (float4*)((float*)dst + i);
        p[0] = a; p[1] = b;
    } else {
        *(u16x8*)((unsigned short*)dst + i) = v;
    }
}

// ---------------------------------------------------------------------------
// Proven 128x128 GEMM: kept for L2 (N=512) and the fallback path.
// ---------------------------------------------------------------------------
template <int RELU, int BIAS, int OUTF, int SWZ>
__global__ __launch_bounds__(256, 2) void gemm_bt(
    const unsigned short* __restrict__ A, const unsigned short* __restrict__ B,
    const float* __restrict__ bias, void* __restrict__ C,
    int M, int N, int K, float alpha,
    long long sA, long long sB, long long sC, const int* __restrict__ flag)
{
    int bxi = blockIdx.x, byi = blockIdx.y;
    if (SWZ) {
        const int id = byi * gridDim.x + bxi;
        bxi = (id >> 3) % gridDim.x;
        byi = (id >> 3) / gridDim.x * 8 + (id & 7);
    }
    const int z = blockIdx.z;
    A += (size_t)z * (size_t)sA;
    B += (size_t)z * (size_t)sB;
    const size_t cofs = (size_t)z * (size_t)sC;

    const int bm = byi * 128;
    const int bn = bxi * 128;
    const int t = threadIdx.x;
    const int lane = t & 63;
    const int w = t >> 6;
    const int wr = (w >> 1) * 64;
    const int wc = (w & 1) * 64;

    __shared__ unsigned short sAt[128 * 32];
    __shared__ unsigned short sBt[128 * 32];

    f32x4 acc[4][4];
#pragma unroll
    for (int i = 0; i < 4; i++)
#pragma unroll
        for (int j = 0; j < 4; j++)
            acc[i][j] = (f32x4){0.f, 0.f, 0.f, 0.f};

    const int tr = t >> 2;
    const int tc = (t & 3) << 3;
    const unsigned short* ga = A + (size_t)(bm + tr) * K + tc;
    const unsigned short* gb = B + (size_t)(bn + tr) * K + tc;
    unsigned short* la = &sAt[tr * 32 + tc];
    unsigned short* lb = &sBt[tr * 32 + tc];

    const int am = wr + (lane & 15);
    const int bn_ = wc + (lane & 15);
    const int ak = (lane >> 4) * 8;

    for (int k0 = 0; k0 < K; k0 += 32) {
        async16(ga, la);
        async16(ga + (size_t)64 * K, la + 64 * 32);
        async16(gb, lb);
        async16(gb + (size_t)64 * K, lb + 64 * 32);
        ga += 32;
        gb += 32;
        __syncthreads();

        bf16x8 af[4], bfr[4];
#pragma unroll
        for (int i = 0; i < 4; i++)
            af[i] = *(const bf16x8*)&sAt[(am + i * 16) * 32 + ak];
#pragma unroll
        for (int j = 0; j < 4; j++)
            bfr[j] = *(const bf16x8*)&sBt[(bn_ + j * 16) * 32 + ak];
#pragma unroll
        for (int i = 0; i < 4; i++)
#pragma unroll
            for (int j = 0; j < 4; j++)
                acc[i][j] = __builtin_amdgcn_mfma_f32_16x16x32_bf16(
                    af[i], bfr[j], acc[i][j], 0, 0, 0);
        __syncthreads();
    }

    const int fl = OUTF ? *flag : 0;
#pragma unroll
    for (int i = 0; i < 4; i++) {
        const int row0 = bm + wr + i * 16 + (lane >> 4) * 4;
#pragma unroll
        for (int j = 0; j < 4; j++) {
            const int col = bn + wc + j * 16 + (lane & 15);
            float bc = 0.f;
            if (BIAS == 1) bc = bias[col];
#pragma unroll
            for (int r = 0; r < 4; r++) {
                float bv = bc;
                if (BIAS == 2) bv = bias[row0 + r];
                float vv = acc[i][j][r] * alpha + bv;
                if (RELU) vv = fmaxf(vv, 0.f);
                const size_t idx = cofs + (size_t)(row0 + r) * N + col;
                if (OUTF && fl) ((float*)C)[idx] = vv;
                else ((unsigned short*)C)[idx] = f2bf(vv);
            }
        }
    }
}

// ---------------------------------------------------------------------------
// R10 gemm8 (session-best): 256x256 tile, BK=32, 8 waves, 4 LDS tile-slots
// of 32 KiB (A slots at 0..64KiB, B slots at 64..128KiB). One phase per
// 32-K tile: {stage tile T+2 -> slot (T+2)&3 | 12 ds_read_b128 | 32 MFMA |
// vmcnt(4) ; barrier}. Per-wave vmcnt before the barrier makes tile T+1
// resident for all waves after it. Swizzle: element octet e stored at LDS
// octet e^((row>>1)&3); read oct = ((lane>>4)^((lane>>1)&3))*8 -> verified
// 0 bank conflicts. Staging: linear LDS dest, inverse-swizzled global src.
// Requires M%256==0, N%256==0, K%32==0, K>=64.
// ---------------------------------------------------------------------------
#define G10_STG(SOFS, KOFS) do {                                               \
    async16(gAs + (KOFS), dA + (SOFS));                                        \
    async16(gAs + (KOFS) + rk128, dA + (SOFS) + 4096);                         \
    async16(gBs + (KOFS), dB + (SOFS));                                        \
    async16(gBs + (KOFS) + rk128, dB + (SOFS) + 4096);                         \
} while (0)

template <int RELU, int BIAS, int OUTF, int SWZ>
__global__ __launch_bounds__(512, 2) void gemm8(
    const unsigned short* __restrict__ A, const unsigned short* __restrict__ B,
    const float* __restrict__ bias, void* __restrict__ C,
    int M, int N, int K, float alpha,
    long long sA, long long sB, long long sC, const int* __restrict__ flag)
{
    extern __shared__ unsigned short lds[];
    (void)M;
    int bxi = blockIdx.x, byi = blockIdx.y;
    if (SWZ) {
        const int id = byi * gridDim.x + bxi;
        bxi = (id >> 3) % gridDim.x;
        byi = (id >> 3) / gridDim.x * 8 + (id & 7);
    }
    const int z = blockIdx.z;
    A += (size_t)z * (size_t)sA;
    B += (size_t)z * (size_t)sB;
    const size_t cofs = (size_t)z * (size_t)sC;

    const int bm = byi * 256;
    const int bn = bxi * 256;
    const int t = threadIdx.x;
    const int lane = t & 63;
    const int w = t >> 6;
    const int wm = w >> 2;
    const int wn = w & 3;

    const int soct = ((t & 3) ^ ((t >> 3) & 3)) << 3;
    const unsigned short* gAs = A + (size_t)(bm + (t >> 2)) * K + soct;
    const unsigned short* gBs = B + (size_t)(bn + (t >> 2)) * K + soct;
    const size_t rk128 = (size_t)128 * K;
    unsigned short* dA = lds + t * 8;
    unsigned short* dB = lds + 32768 + t * 8;

    const int l15 = lane & 15;
    const int oct = (((lane >> 4) ^ ((lane >> 1) & 3)) << 3);
    const int aoff = (wm * 128 + l15) * 32 + oct;
    const int boff = (wn * 64 + l15) * 32 + oct;

    f32x4 acc[8][4];
#pragma unroll
    for (int i = 0; i < 8; i++)
#pragma unroll
        for (int j = 0; j < 4; j++)
            acc[i][j] = (f32x4){0.f, 0.f, 0.f, 0.f};

    G10_STG(0, 0);
    G10_STG(8192, 32);
    asm volatile("s_waitcnt vmcnt(4)" ::: "memory");
    __builtin_amdgcn_s_barrier();
    asm volatile("" ::: "memory");

    const int NT = K >> 5;
    for (int T = 0; T < NT; ++T) {
        if (T + 2 < NT) {
            const int so = ((T + 2) & 3) * 8192;
            const int ko = (T + 2) << 5;
            G10_STG(so, ko);
        }
        const int sr = (T & 3) * 8192;
        const unsigned short* pa = lds + sr + aoff;
        const unsigned short* pb = lds + 32768 + sr + boff;
        bf16x8 bb[4], a[8];
#pragma unroll
        for (int n = 0; n < 4; n++)
            bb[n] = *(const bf16x8*)(pb + n * 512);
#pragma unroll
        for (int m = 0; m < 8; m++)
            a[m] = *(const bf16x8*)(pa + m * 512);
        __builtin_amdgcn_s_setprio(1);
#pragma unroll
        for (int m = 0; m < 8; m++)
#pragma unroll
            for (int n = 0; n < 4; n++)
                acc[m][n] = __builtin_amdgcn_mfma_f32_16x16x32_bf16(
                    a[m], bb[n], acc[m][n], 0, 0, 0);
        __builtin_amdgcn_s_setprio(0);
        if (T + 1 < NT) {
            if (T + 2 < NT) {
                asm volatile("s_waitcnt vmcnt(4)" ::: "memory");
            } else {
                asm volatile("s_waitcnt vmcnt(0)" ::: "memory");
            }
            __builtin_amdgcn_s_barrier();
            asm volatile("" ::: "memory");
        }
    }

    const int fl = OUTF ? *flag : 0;
#pragma unroll
    for (int mi = 0; mi < 8; mi++) {
        const int row0 = bm + wm * 128 + mi * 16 + (lane >> 4) * 4;
#pragma unroll
        for (int n = 0; n < 4; n++) {
            const int col = bn + wn * 64 + n * 16 + (lane & 15);
            float bc = 0.f;
            if (BIAS == 1) bc = bias[col];
#pragma unroll
            for (int r = 0; r < 4; r++) {
                float bv = bc;
                if (BIAS == 2) bv = bias[row0 + r];
                float vv = acc[mi][n][r] * alpha + bv;
                if (RELU) vv = fmaxf(vv, 0.f);
                const size_t idx = cofs + (size_t)(row0 + r) * N + col;
                if (OUTF && fl) ((float*)C)[idx] = vv;
                else ((unsigned short*)C)[idx] = f2bf(vv);
            }
        }
    }
}

// ---------------------------------------------------------------------------
__global__ __launch_bounds__(256) void softmax_rows(unsigned short* S, int n)
{
    const size_t row = blockIdx.x;
    unsigned short* p = S + row * (size_t)n;
    const int t = threadIdx.x;
    const int lane = t & 63;
    const int wave = t >> 6;

    u16x8 v = *(const u16x8*)(p + t * 8);
    float f[8];
    float m = -3.0e38f;
#pragma unroll
    for (int i = 0; i < 8; i++) {
        f[i] = bf2f(v[i]);
        m = fmaxf(m, f[i]);
    }
#pragma unroll
    for (int off = 32; off; off >>= 1) m = fmaxf(m, __shfl_xor(m, off, 64));
    __shared__ float redm[4];
    if (lane == 0) redm[wave] = m;
    __syncthreads();
    m = fmaxf(fmaxf(redm[0], redm[1]), fmaxf(redm[2], redm[3]));

    float e[8];
    float s = 0.f;
#pragma unroll
    for (int i = 0; i < 8; i++) {
        e[i] = __expf(f[i] - m);
        s += e[i];
    }
#pragma unroll
    for (int off = 32; off; off >>= 1) s += __shfl_xor(s, off, 64);
    __shared__ float reds[4];
    if (lane == 0) reds[wave] = s;
    __syncthreads();
    s = reds[0] + reds[1] + reds[2] + reds[3];
    const float inv = 1.0f / s;

    u16x8 o;
#pragma unroll
    for (int i = 0; i < 8; i++) o[i] = f2bf(e[i] * inv);
    *(u16x8*)(p + t * 8) = o;
}

// ---------------------------------------------------------------------------
extern "C" void kernel_launch(void* const* d_in, const int* in_sizes, int n_in,
                              void* d_out, int out_size, void* d_ws, size_t ws_size,
                              hipStream_t stream)
{
    const void* x  = d_in[0];
    const void* y  = d_in[1];
    const void* W1 = d_in[2];
    const void* b1 = d_in[3];
    const void* W2 = d_in[4];
    const void* b2 = d_in[5];
    const void* W3 = d_in[6];
    const void* b3 = d_in[7];
    const void* W4 = d_in[8];
    const void* b4 = d_in[9];
    const void* Wq = d_in[10];
    const void* bq = d_in[11];
    const void* Wk = d_in[12];
    const void* bk = d_in[13];
    const void* Wv = d_in[14];
    const void* bv = d_in[15];

    int* flag = (int*)d_ws;
    float* fb = (float*)((char*)d_ws + 64);
    unsigned short* arena = (unsigned short*)((char*)d_ws + 64 + 7 * 1024 * 4);
    const size_t baseB = 64 + 7 * 1024 * 4;
    const size_t MEG = 1024ull * 1024ull;

    auto needB = [&](int G, bool direct) -> size_t {
        return baseB + 2ull * ((6 + 16 + (size_t)G * 6 + (direct ? 0 : 16)) * MEG);
    };
    int G; bool direct;
    if (ws_size >= needB(8, true))      { G = 8; direct = true;  }
    else if (ws_size >= needB(4, false)) { G = 4; direct = false; }
    else if (ws_size >= needB(2, false)) { G = 2; direct = false; }
    else                                 { G = 1; direct = false; }

    unsigned short* W1t = arena;
    unsigned short* W2t = W1t + 1 * MEG;
    unsigned short* W3t = W2t + MEG / 2;
    unsigned short* W4t = W3t + MEG / 2;
    unsigned short* Wqt = W4t + 1 * MEG;
    unsigned short* Wkt = Wqt + 1 * MEG;
    unsigned short* Wvt = Wkt + 1 * MEG;
    unsigned short* XC  = Wvt + 1 * MEG;
    unsigned short* VT  = XC + 16 * MEG;
    unsigned short* SBUF = VT + (size_t)G * 2 * MEG;
    unsigned short* OUTS = SBUF + (size_t)G * 4 * MEG;

    unsigned short* PA = (unsigned short*)d_out;
    unsigned short* PB = PA + 16 * MEG;

    float* fb1 = fb;
    float* fb2 = fb + 1024;
    float* fb3 = fb + 2048;
    float* fb4 = fb + 3072;
    float* fbq = fb + 4096;
    float* fbk = fb + 5120;
    float* fbv = fb + 6144;

    const dim3 blk(256);
    const dim3 blk8(512);
    const int LDS8 = 131072;
    const int NE = 16 * 1024 * 1024;
    const int Mx = 16384;
    const long long Z0 = 0;
    const long long sQK = 2048ll * 1024;
    const long long sS  = 2048ll * 2048;

    (void)hipFuncSetAttribute((const void*)&gemm8<1, 1, 0, 1>,
                              hipFuncAttributeMaxDynamicSharedMemorySize, LDS8);
    (void)hipFuncSetAttribute((const void*)&gemm8<0, 1, 0, 1>,
                              hipFuncAttributeMaxDynamicSharedMemorySize, LDS8);
    (void)hipFuncSetAttribute((const void*)&gemm8<0, 2, 0, 0>,
                              hipFuncAttributeMaxDynamicSharedMemorySize, LDS8);
    (void)hipFuncSetAttribute((const void*)&gemm8<0, 0, 0, 1>,
                              hipFuncAttributeMaxDynamicSharedMemorySize, LDS8);
    (void)hipFuncSetAttribute((const void*)&gemm8<0, 0, 1, 1>,
                              hipFuncAttributeMaxDynamicSharedMemorySize, LDS8);

    detect_dtype<<<1, 64, 0, stream>>>((const unsigned short*)W1, flag);
    conv_bias_all<<<28, blk, 0, stream>>>(b1, b2, b3, b4, bq, bk, bv, fb, flag);
    conv_weight_t7<<<dim3(32, 32, 7), blk, 0, stream>>>(
        W1, W1t, W4, W4t, Wq, Wqt, Wk, Wkt, Wv, Wvt, W2, W2t, W3, W3t, flag);

    conv_to_bf16<<<8192, blk, 0, stream>>>(x, XC, NE, flag);

    // MLP: L1/L3/L4 on gemm8 (256x256), L2 (N=512) on proven gemm_bt
    gemm8<1, 1, 0, 1><<<dim3(4, 64), blk8, LDS8, stream>>>(
        XC, W1t, fb1, PA, Mx, 1024, 1024, 1.f, Z0, Z0, Z0, flag);
    gemm_bt<1, 1, 0, 1><<<dim3(4, 128), blk, 0, stream>>>(
        PA, W2t, fb2, PB, Mx, 512, 1024, 1.f, Z0, Z0, Z0, flag);
    gemm8<1, 1, 0, 1><<<dim3(4, 64), blk8, LDS8, stream>>>(
        PB, W3t, fb3, PA, Mx, 1024, 512, 1.f, Z0, Z0, Z0, flag);
    gemm8<1, 1, 0, 1><<<dim3(4, 64), blk8, LDS8, stream>>>(
        PA, W4t, fb4, PB, Mx, 1024, 1024, 1.f, Z0, Z0, Z0, flag);

    // q -> PA ; y -> XC ; k -> PB
    gemm8<0, 1, 0, 1><<<dim3(4, 64), blk8, LDS8, stream>>>(
        PB, Wqt, fbq, PA, Mx, 1024, 1024, 1.f, Z0, Z0, Z0, flag);
    conv_to_bf16<<<8192, blk, 0, stream>>>(y, XC, NE, flag);
    gemm8<0, 1, 0, 1><<<dim3(4, 64), blk8, LDS8, stream>>>(
        XC, Wkt, fbk, PB, Mx, 1024, 1024, 1.f, Z0, Z0, Z0, flag);

    if (direct) {
        gemm8<0, 2, 0, 0><<<dim3(8, 4, 8), blk8, LDS8, stream>>>(
            Wvt, XC, fbv, VT, 1024, 2048, 1024, 1.f, Z0, sQK, sQK, flag);
        gemm8<0, 0, 0, 1><<<dim3(8, 8, 8), blk8, LDS8, stream>>>(
            PA, PB, nullptr, SBUF, 2048, 2048, 1024, 0.03125f, sQK, sQK, sS, flag);
        softmax_rows<<<dim3(8 * 2048), blk, 0, stream>>>(SBUF, 2048);
        gemm8<0, 0, 1, 1><<<dim3(4, 8, 8), blk8, LDS8, stream>>>(
            SBUF, VT, nullptr, d_out, 2048, 1024, 2048, 1.f, sS, sQK, sQK, flag);
    } else {
        for (int g = 0; g < 8; g += G) {
            const size_t off = (size_t)g * 2048 * 1024;
            gemm_bt<0, 2, 0, 0><<<dim3(16, 8, G), blk, 0, stream>>>(
                Wvt, XC + off, fbv, VT, 1024, 2048, 1024, 1.f, Z0, sQK, sQK, flag);
            gemm_bt<0, 0, 0, 1><<<dim3(16, 16, G), blk, 0, stream>>>(
                PA + off, PB + off, nullptr, SBUF, 2048, 2048, 1024, 0.03125f, sQK, sQK, sS, flag);
            softmax_rows<<<dim3(G * 2048), blk, 0, stream>>>(SBUF, 2048);
            gemm_bt<0, 0, 0, 1><<<dim3(8, 16, G), blk, 0, stream>>>(
                SBUF, VT, nullptr, OUTS + off, 2048, 1024, 2048, 1.f, sS, sQK, sQK, flag);
        }
        write_out<<<8192, blk, 0, stream>>>(OUTS, d_out, NE, flag);
    }
}

// Round 13
// 608.930 us; speedup vs baseline: 1.1896x; 1.0002x over previous
//
#include <hip/hip_runtime.h>
#include <stdint.h>

// CrossAttention, fp32/bf16 I/O autodetect, all-bf16 MFMA pipeline.
// R18 = R10/R17 (session-best, 603-609us) + two safe cleanups:
//  (1) L2 (N=512) moved from gemm_bt (128-tile, ~763 TF class) to gemm8
//      (256x512 via grid dim3(2,64); swizzle bijective for gx=2). -3..5us.
//  (2) conv_to_bf16(y) issued right after L1 (XC's x-content dead there).
// Ledger: R6-R16 measured schedule/locality/occupancy/wave-geometry/fusion
// variants; all pinned at ~865-905 TF (36% MfmaUtil) on scores/PV or
// regressed. This is the structural plateau of the compiler-scheduled
// barrier-synchronized plain-HIP GEMM family on gfx950.

typedef __attribute__((ext_vector_type(8))) short bf16x8;
typedef __attribute__((ext_vector_type(4))) float f32x4;
typedef __attribute__((ext_vector_type(8))) unsigned short u16x8;

__device__ __forceinline__ float bf2f(unsigned short u) {
    return __uint_as_float(((unsigned int)u) << 16);
}
__device__ __forceinline__ unsigned short f2bf(float f) {
    unsigned int u = __float_as_uint(f);
    unsigned int r = (u + 0x7fffu + ((u >> 16) & 1u)) >> 16;
    return (unsigned short)r;
}

__device__ __forceinline__ void async16(const void* g, void* l) {
    __builtin_amdgcn_global_load_lds(
        (const __attribute__((address_space(1))) unsigned int*)g,
        (__attribute__((address_space(3))) unsigned int*)l,
        16, 0, 0);
}

// ---------------------------------------------------------------------------
__global__ __launch_bounds__(64) void detect_dtype(
    const unsigned short* __restrict__ w, int* __restrict__ flag)
{
    const int t = threadIdx.x;
    int cnt = 0;
    for (int i = t; i < 4096; i += 64) {
        const unsigned e = (w[i] >> 7) & 0xFF;
        cnt += (e >= 140) ? 1 : 0;
    }
#pragma unroll
    for (int off = 32; off; off >>= 1) cnt += __shfl_xor(cnt, off, 64);
    if (t == 0) flag[0] = (cnt >= 8) ? 1 : 0;
}

// ---------------------------------------------------------------------------
__global__ __launch_bounds__(256) void conv_bias_all(
    const void* b1, const void* b2, const void* b3, const void* b4,
    const void* bq, const void* bk, const void* bv,
    float* __restrict__ out, const int* __restrict__ flag)
{
    const int i = blockIdx.x * 256 + threadIdx.x;
    const int slot = i >> 10, idx = i & 1023;
    if (slot == 1 && idx >= 512) return;
    const void* src = (slot == 0) ? b1 : (slot == 1) ? b2 : (slot == 2) ? b3 :
                      (slot == 3) ? b4 : (slot == 4) ? bq : (slot == 5) ? bk : bv;
    out[i] = (*flag) ? ((const float*)src)[idx]
                     : bf2f(((const unsigned short*)src)[idx]);
}

// ---------------------------------------------------------------------------
__device__ __forceinline__ void wt_body(
    const void* in, unsigned short* out, int R, int C, int f)
{
    __shared__ unsigned short tile[32][33];
    const int bc = blockIdx.x * 32;
    const int br = blockIdx.y * 32;
    const int x = threadIdx.x & 31;
    const int y = threadIdx.x >> 5;
#pragma unroll
    for (int i = 0; i < 4; i++) {
        const int r = y + i * 8;
        unsigned short v;
        if (f) v = f2bf(((const float*)in)[(size_t)(br + r) * C + bc + x]);
        else   v = ((const unsigned short*)in)[(size_t)(br + r) * C + bc + x];
        tile[r][x] = v;
    }
    __syncthreads();
#pragma unroll
    for (int i = 0; i < 4; i++) {
        const int r = y + i * 8;
        out[(size_t)(bc + r) * R + br + x] = tile[x][r];
    }
}

__global__ __launch_bounds__(256) void conv_weight_t7(
    const void* i0, unsigned short* o0, const void* i1, unsigned short* o1,
    const void* i2, unsigned short* o2, const void* i3, unsigned short* o3,
    const void* i4, unsigned short* o4, const void* i5, unsigned short* o5,
    const void* i6, unsigned short* o6, const int* flag)
{
    const int z = blockIdx.z;
    if (z == 5) {
        if (blockIdx.x >= 16) return;
        wt_body(i5, o5, 1024, 512, *flag);
        return;
    }
    if (z == 6) {
        if (blockIdx.y >= 16) return;
        wt_body(i6, o6, 512, 1024, *flag);
        return;
    }
    const void* in = (z == 0) ? i0 : (z == 1) ? i1 : (z == 2) ? i2 : (z == 3) ? i3 : i4;
    unsigned short* out = (z == 0) ? o0 : (z == 1) ? o1 : (z == 2) ? o2 : (z == 3) ? o3 : o4;
    wt_body(in, out, 1024, 1024, *flag);
}

__global__ __launch_bounds__(256) void conv_to_bf16(
    const void* __restrict__ in, unsigned short* __restrict__ out,
    int n, const int* __restrict__ flag)
{
    const int i = (blockIdx.x * 256 + threadIdx.x) * 8;
    if (i >= n) return;
    if (*flag) {
        const float4* p = (const float4*)((const float*)in + i);
        const float4 a = p[0], b = p[1];
        u16x8 o;
        o[0] = f2bf(a.x); o[1] = f2bf(a.y); o[2] = f2bf(a.z); o[3] = f2bf(a.w);
        o[4] = f2bf(b.x); o[5] = f2bf(b.y); o[6] = f2bf(b.z); o[7] = f2bf(b.w);
        *(u16x8*)(out + i) = o;
    } else {
        *(u16x8*)(out + i) = *(const u16x8*)((const unsigned short*)in + i);
    }
}

__global__ __launch_bounds__(256) void write_out(
    const unsigned short* __restrict__ src, void* __restrict__ dst,
    int n, const int* __restrict__ flag)
{
    const int i = (blockIdx.x * 256 + threadIdx.x) * 8;
    if (i >= n) return;
    const u16x8 v = *(const u16x8*)(src + i);
    if (*flag) {
        float4 a, b;
        a.x = bf2f(v[0]); a.y = bf2f(v[1]); a.z = bf2f(v[2]); a.w = bf2f(v[3]);
        b.x = bf2f(v[4]); b.y = bf2f(v[5]); b.z = bf2f(v[6]); b.w = bf2f(v[7]);
        float4* p = (float4*)((float*)dst + i);
        p[0] = a; p[1] = b;
    } else {
        *(u16x8*)((unsigned short*)dst + i) = v;
    }
}

// ---------------------------------------------------------------------------
// Proven 128x128 GEMM: kept for the low-workspace fallback path.
// ---------------------------------------------------------------------------
template <int RELU, int BIAS, int OUTF, int SWZ>
__global__ __launch_bounds__(256, 2) void gemm_bt(
    const unsigned short* __restrict__ A, const unsigned short* __restrict__ B,
    const float* __restrict__ bias, void* __restrict__ C,
    int M, int N, int K, float alpha,
    long long sA, long long sB, long long sC, const int* __restrict__ flag)
{
    int bxi = blockIdx.x, byi = blockIdx.y;
    if (SWZ) {
        const int id = byi * gridDim.x + bxi;
        bxi = (id >> 3) % gridDim.x;
        byi = (id >> 3) / gridDim.x * 8 + (id & 7);
    }
    const int z = blockIdx.z;
    A += (size_t)z * (size_t)sA;
    B += (size_t)z * (size_t)sB;
    const size_t cofs = (size_t)z * (size_t)sC;

    const int bm = byi * 128;
    const int bn = bxi * 128;
    const int t = threadIdx.x;
    const int lane = t & 63;
    const int w = t >> 6;
    const int wr = (w >> 1) * 64;
    const int wc = (w & 1) * 64;

    __shared__ unsigned short sAt[128 * 32];
    __shared__ unsigned short sBt[128 * 32];

    f32x4 acc[4][4];
#pragma unroll
    for (int i = 0; i < 4; i++)
#pragma unroll
        for (int j = 0; j < 4; j++)
            acc[i][j] = (f32x4){0.f, 0.f, 0.f, 0.f};

    const int tr = t >> 2;
    const int tc = (t & 3) << 3;
    const unsigned short* ga = A + (size_t)(bm + tr) * K + tc;
    const unsigned short* gb = B + (size_t)(bn + tr) * K + tc;
    unsigned short* la = &sAt[tr * 32 + tc];
    unsigned short* lb = &sBt[tr * 32 + tc];

    const int am = wr + (lane & 15);
    const int bn_ = wc + (lane & 15);
    const int ak = (lane >> 4) * 8;

    for (int k0 = 0; k0 < K; k0 += 32) {
        async16(ga, la);
        async16(ga + (size_t)64 * K, la + 64 * 32);
        async16(gb, lb);
        async16(gb + (size_t)64 * K, lb + 64 * 32);
        ga += 32;
        gb += 32;
        __syncthreads();

        bf16x8 af[4], bfr[4];
#pragma unroll
        for (int i = 0; i < 4; i++)
            af[i] = *(const bf16x8*)&sAt[(am + i * 16) * 32 + ak];
#pragma unroll
        for (int j = 0; j < 4; j++)
            bfr[j] = *(const bf16x8*)&sBt[(bn_ + j * 16) * 32 + ak];
#pragma unroll
        for (int i = 0; i < 4; i++)
#pragma unroll
            for (int j = 0; j < 4; j++)
                acc[i][j] = __builtin_amdgcn_mfma_f32_16x16x32_bf16(
                    af[i], bfr[j], acc[i][j], 0, 0, 0);
        __syncthreads();
    }

    const int fl = OUTF ? *flag : 0;
#pragma unroll
    for (int i = 0; i < 4; i++) {
        const int row0 = bm + wr + i * 16 + (lane >> 4) * 4;
#pragma unroll
        for (int j = 0; j < 4; j++) {
            const int col = bn + wc + j * 16 + (lane & 15);
            float bc = 0.f;
            if (BIAS == 1) bc = bias[col];
#pragma unroll
            for (int r = 0; r < 4; r++) {
                float bv = bc;
                if (BIAS == 2) bv = bias[row0 + r];
                float vv = acc[i][j][r] * alpha + bv;
                if (RELU) vv = fmaxf(vv, 0.f);
                const size_t idx = cofs + (size_t)(row0 + r) * N + col;
                if (OUTF && fl) ((float*)C)[idx] = vv;
                else ((unsigned short*)C)[idx] = f2bf(vv);
            }
        }
    }
}

// ---------------------------------------------------------------------------
// R10 gemm8 (session-best): 256x256 tile, BK=32, 8 waves, 4 LDS tile-slots
// of 32 KiB (A slots at 0..64KiB, B slots at 64..128KiB). One phase per
// 32-K tile: {stage tile T+2 -> slot (T+2)&3 | 12 ds_read_b128 | 32 MFMA |
// vmcnt(4) ; barrier}. Per-wave vmcnt before the barrier makes tile T+1
// resident for all waves after it. Swizzle: element octet e stored at LDS
// octet e^((row>>1)&3); read oct = ((lane>>4)^((lane>>1)&3))*8 -> verified
// 0 bank conflicts. Staging: linear LDS dest, inverse-swizzled global src.
// Requires M%256==0, N%256==0, K%32==0, K>=64.
// ---------------------------------------------------------------------------
#define G10_STG(SOFS, KOFS) do {                                               \
    async16(gAs + (KOFS), dA + (SOFS));                                        \
    async16(gAs + (KOFS) + rk128, dA + (SOFS) + 4096);                         \
    async16(gBs + (KOFS), dB + (SOFS));                                        \
    async16(gBs + (KOFS) + rk128, dB + (SOFS) + 4096);                         \
} while (0)

template <int RELU, int BIAS, int OUTF, int SWZ>
__global__ __launch_bounds__(512, 2) void gemm8(
    const unsigned short* __restrict__ A, const unsigned short* __restrict__ B,
    const float* __restrict__ bias, void* __restrict__ C,
    int M, int N, int K, float alpha,
    long long sA, long long sB, long long sC, const int* __restrict__ flag)
{
    extern __shared__ unsigned short lds[];
    (void)M;
    int bxi = blockIdx.x, byi = blockIdx.y;
    if (SWZ) {
        const int id = byi * gridDim.x + bxi;
        bxi = (id >> 3) % gridDim.x;
        byi = (id >> 3) / gridDim.x * 8 + (id & 7);
    }
    const int z = blockIdx.z;
    A += (size_t)z * (size_t)sA;
    B += (size_t)z * (size_t)sB;
    const size_t cofs = (size_t)z * (size_t)sC;

    const int bm = byi * 256;
    const int bn = bxi * 256;
    const int t = threadIdx.x;
    const int lane = t & 63;
    const int w = t >> 6;
    const int wm = w >> 2;
    const int wn = w & 3;

    const int soct = ((t & 3) ^ ((t >> 3) & 3)) << 3;
    const unsigned short* gAs = A + (size_t)(bm + (t >> 2)) * K + soct;
    const unsigned short* gBs = B + (size_t)(bn + (t >> 2)) * K + soct;
    const size_t rk128 = (size_t)128 * K;
    unsigned short* dA = lds + t * 8;
    unsigned short* dB = lds + 32768 + t * 8;

    const int l15 = lane & 15;
    const int oct = (((lane >> 4) ^ ((lane >> 1) & 3)) << 3);
    const int aoff = (wm * 128 + l15) * 32 + oct;
    const int boff = (wn * 64 + l15) * 32 + oct;

    f32x4 acc[8][4];
#pragma unroll
    for (int i = 0; i < 8; i++)
#pragma unroll
        for (int j = 0; j < 4; j++)
            acc[i][j] = (f32x4){0.f, 0.f, 0.f, 0.f};

    G10_STG(0, 0);
    G10_STG(8192, 32);
    asm volatile("s_waitcnt vmcnt(4)" ::: "memory");
    __builtin_amdgcn_s_barrier();
    asm volatile("" ::: "memory");

    const int NT = K >> 5;
    for (int T = 0; T < NT; ++T) {
        if (T + 2 < NT) {
            const int so = ((T + 2) & 3) * 8192;
            const int ko = (T + 2) << 5;
            G10_STG(so, ko);
        }
        const int sr = (T & 3) * 8192;
        const unsigned short* pa = lds + sr + aoff;
        const unsigned short* pb = lds + 32768 + sr + boff;
        bf16x8 bb[4], a[8];
#pragma unroll
        for (int n = 0; n < 4; n++)
            bb[n] = *(const bf16x8*)(pb + n * 512);
#pragma unroll
        for (int m = 0; m < 8; m++)
            a[m] = *(const bf16x8*)(pa + m * 512);
        __builtin_amdgcn_s_setprio(1);
#pragma unroll
        for (int m = 0; m < 8; m++)
#pragma unroll
            for (int n = 0; n < 4; n++)
                acc[m][n] = __builtin_amdgcn_mfma_f32_16x16x32_bf16(
                    a[m], bb[n], acc[m][n], 0, 0, 0);
        __builtin_amdgcn_s_setprio(0);
        if (T + 1 < NT) {
            if (T + 2 < NT) {
                asm volatile("s_waitcnt vmcnt(4)" ::: "memory");
            } else {
                asm volatile("s_waitcnt vmcnt(0)" ::: "memory");
            }
            __builtin_amdgcn_s_barrier();
            asm volatile("" ::: "memory");
        }
    }

    const int fl = OUTF ? *flag : 0;
#pragma unroll
    for (int mi = 0; mi < 8; mi++) {
        const int row0 = bm + wm * 128 + mi * 16 + (lane >> 4) * 4;
#pragma unroll
        for (int n = 0; n < 4; n++) {
            const int col = bn + wn * 64 + n * 16 + (lane & 15);
            float bc = 0.f;
            if (BIAS == 1) bc = bias[col];
#pragma unroll
            for (int r = 0; r < 4; r++) {
                float bv = bc;
                if (BIAS == 2) bv = bias[row0 + r];
                float vv = acc[mi][n][r] * alpha + bv;
                if (RELU) vv = fmaxf(vv, 0.f);
                const size_t idx = cofs + (size_t)(row0 + r) * N + col;
                if (OUTF && fl) ((float*)C)[idx] = vv;
                else ((unsigned short*)C)[idx] = f2bf(vv);
            }
        }
    }
}

// ---------------------------------------------------------------------------
__global__ __launch_bounds__(256) void softmax_rows(unsigned short* S, int n)
{
    const size_t row = blockIdx.x;
    unsigned short* p = S + row * (size_t)n;
    const int t = threadIdx.x;
    const int lane = t & 63;
    const int wave = t >> 6;

    u16x8 v = *(const u16x8*)(p + t * 8);
    float f[8];
    float m = -3.0e38f;
#pragma unroll
    for (int i = 0; i < 8; i++) {
        f[i] = bf2f(v[i]);
        m = fmaxf(m, f[i]);
    }
#pragma unroll
    for (int off = 32; off; off >>= 1) m = fmaxf(m, __shfl_xor(m, off, 64));
    __shared__ float redm[4];
    if (lane == 0) redm[wave] = m;
    __syncthreads();
    m = fmaxf(fmaxf(redm[0], redm[1]), fmaxf(redm[2], redm[3]));

    float e[8];
    float s = 0.f;
#pragma unroll
    for (int i = 0; i < 8; i++) {
        e[i] = __expf(f[i] - m);
        s += e[i];
    }
#pragma unroll
    for (int off = 32; off; off >>= 1) s += __shfl_xor(s, off, 64);
    __shared__ float reds[4];
    if (lane == 0) reds[wave] = s;
    __syncthreads();
    s = reds[0] + reds[1] + reds[2] + reds[3];
    const float inv = 1.0f / s;

    u16x8 o;
#pragma unroll
    for (int i = 0; i < 8; i++) o[i] = f2bf(e[i] * inv);
    *(u16x8*)(p + t * 8) = o;
}

// ---------------------------------------------------------------------------
extern "C" void kernel_launch(void* const* d_in, const int* in_sizes, int n_in,
                              void* d_out, int out_size, void* d_ws, size_t ws_size,
                              hipStream_t stream)
{
    const void* x  = d_in[0];
    const void* y  = d_in[1];
    const void* W1 = d_in[2];
    const void* b1 = d_in[3];
    const void* W2 = d_in[4];
    const void* b2 = d_in[5];
    const void* W3 = d_in[6];
    const void* b3 = d_in[7];
    const void* W4 = d_in[8];
    const void* b4 = d_in[9];
    const void* Wq = d_in[10];
    const void* bq = d_in[11];
    const void* Wk = d_in[12];
    const void* bk = d_in[13];
    const void* Wv = d_in[14];
    const void* bv = d_in[15];

    int* flag = (int*)d_ws;
    float* fb = (float*)((char*)d_ws + 64);
    unsigned short* arena = (unsigned short*)((char*)d_ws + 64 + 7 * 1024 * 4);
    const size_t baseB = 64 + 7 * 1024 * 4;
    const size_t MEG = 1024ull * 1024ull;

    auto needB = [&](int G, bool direct) -> size_t {
        return baseB + 2ull * ((6 + 16 + (size_t)G * 6 + (direct ? 0 : 16)) * MEG);
    };
    int G; bool direct;
    if (ws_size >= needB(8, true))      { G = 8; direct = true;  }
    else if (ws_size >= needB(4, false)) { G = 4; direct = false; }
    else if (ws_size >= needB(2, false)) { G = 2; direct = false; }
    else                                 { G = 1; direct = false; }

    unsigned short* W1t = arena;
    unsigned short* W2t = W1t + 1 * MEG;
    unsigned short* W3t = W2t + MEG / 2;
    unsigned short* W4t = W3t + MEG / 2;
    unsigned short* Wqt = W4t + 1 * MEG;
    unsigned short* Wkt = Wqt + 1 * MEG;
    unsigned short* Wvt = Wkt + 1 * MEG;
    unsigned short* XC  = Wvt + 1 * MEG;
    unsigned short* VT  = XC + 16 * MEG;
    unsigned short* SBUF = VT + (size_t)G * 2 * MEG;
    unsigned short* OUTS = SBUF + (size_t)G * 4 * MEG;

    unsigned short* PA = (unsigned short*)d_out;
    unsigned short* PB = PA + 16 * MEG;

    float* fb1 = fb;
    float* fb2 = fb + 1024;
    float* fb3 = fb + 2048;
    float* fb4 = fb + 3072;
    float* fbq = fb + 4096;
    float* fbk = fb + 5120;
    float* fbv = fb + 6144;

    const dim3 blk(256);
    const dim3 blk8(512);
    const int LDS8 = 131072;
    const int NE = 16 * 1024 * 1024;
    const int Mx = 16384;
    const long long Z0 = 0;
    const long long sQK = 2048ll * 1024;
    const long long sS  = 2048ll * 2048;

    (void)hipFuncSetAttribute((const void*)&gemm8<1, 1, 0, 1>,
                              hipFuncAttributeMaxDynamicSharedMemorySize, LDS8);
    (void)hipFuncSetAttribute((const void*)&gemm8<0, 1, 0, 1>,
                              hipFuncAttributeMaxDynamicSharedMemorySize, LDS8);
    (void)hipFuncSetAttribute((const void*)&gemm8<0, 2, 0, 0>,
                              hipFuncAttributeMaxDynamicSharedMemorySize, LDS8);
    (void)hipFuncSetAttribute((const void*)&gemm8<0, 0, 0, 1>,
                              hipFuncAttributeMaxDynamicSharedMemorySize, LDS8);
    (void)hipFuncSetAttribute((const void*)&gemm8<0, 0, 1, 1>,
                              hipFuncAttributeMaxDynamicSharedMemorySize, LDS8);

    detect_dtype<<<1, 64, 0, stream>>>((const unsigned short*)W1, flag);
    conv_bias_all<<<28, blk, 0, stream>>>(b1, b2, b3, b4, bq, bk, bv, fb, flag);
    conv_weight_t7<<<dim3(32, 32, 7), blk, 0, stream>>>(
        W1, W1t, W4, W4t, Wq, Wqt, Wk, Wkt, Wv, Wvt, W2, W2t, W3, W3t, flag);

    conv_to_bf16<<<8192, blk, 0, stream>>>(x, XC, NE, flag);

    // MLP: all four layers on gemm8 (L2: N=512 -> grid dim3(2,64))
    gemm8<1, 1, 0, 1><<<dim3(4, 64), blk8, LDS8, stream>>>(
        XC, W1t, fb1, PA, Mx, 1024, 1024, 1.f, Z0, Z0, Z0, flag);
    // XC's x-content dead after L1: convert y now (enables clean q/k/v tail)
    conv_to_bf16<<<8192, blk, 0, stream>>>(y, XC, NE, flag);
    gemm8<1, 1, 0, 1><<<dim3(2, 64), blk8, LDS8, stream>>>(
        PA, W2t, fb2, PB, Mx, 512, 1024, 1.f, Z0, Z0, Z0, flag);
    gemm8<1, 1, 0, 1><<<dim3(4, 64), blk8, LDS8, stream>>>(
        PB, W3t, fb3, PA, Mx, 1024, 512, 1.f, Z0, Z0, Z0, flag);
    gemm8<1, 1, 0, 1><<<dim3(4, 64), blk8, LDS8, stream>>>(
        PA, W4t, fb4, PB, Mx, 1024, 1024, 1.f, Z0, Z0, Z0, flag);

    // q -> PA ; k -> PB happens after q reads PB (serialized stream: safe order
    // is q first, then k overwrites PB's h4)
    gemm8<0, 1, 0, 1><<<dim3(4, 64), blk8, LDS8, stream>>>(
        PB, Wqt, fbq, PA, Mx, 1024, 1024, 1.f, Z0, Z0, Z0, flag);
    gemm8<0, 1, 0, 1><<<dim3(4, 64), blk8, LDS8, stream>>>(
        XC, Wkt, fbk, PB, Mx, 1024, 1024, 1.f, Z0, Z0, Z0, flag);

    if (direct) {
        gemm8<0, 2, 0, 0><<<dim3(8, 4, 8), blk8, LDS8, stream>>>(
            Wvt, XC, fbv, VT, 1024, 2048, 1024, 1.f, Z0, sQK, sQK, flag);
        gemm8<0, 0, 0, 1><<<dim3(8, 8, 8), blk8, LDS8, stream>>>(
            PA, PB, nullptr, SBUF, 2048, 2048, 1024, 0.03125f, sQK, sQK, sS, flag);
        softmax_rows<<<dim3(8 * 2048), blk, 0, stream>>>(SBUF, 2048);
        gemm8<0, 0, 1, 1><<<dim3(4, 8, 8), blk8, LDS8, stream>>>(
            SBUF, VT, nullptr, d_out, 2048, 1024, 2048, 1.f, sS, sQK, sQK, flag);
    } else {
        for (int g = 0; g < 8; g += G) {
            const size_t off = (size_t)g * 2048 * 1024;
            gemm_bt<0, 2, 0, 0><<<dim3(16, 8, G), blk, 0, stream>>>(
                Wvt, XC + off, fbv, VT, 1024, 2048, 1024, 1.f, Z0, sQK, sQK, flag);
            gemm_bt<0, 0, 0, 1><<<dim3(16, 16, G), blk, 0, stream>>>(
                PA + off, PB + off, nullptr, SBUF, 2048, 2048, 1024, 0.03125f, sQK, sQK, sS, flag);
            softmax_rows<<<dim3(G * 2048), blk, 0, stream>>>(SBUF, 2048);
            gemm_bt<0, 0, 0, 1><<<dim3(8, 16, G), blk, 0, stream>>>(
                SBUF, VT, nullptr, OUTS + off, 2048, 1024, 2048, 1.f, sS, sQK, sQK, flag);
        }
        write_out<<<8192, blk, 0, stream>>>(OUTS, d_out, NE, flag);
    }
}